// Round 6
// baseline (654.128 us; speedup 1.0000x reference)
//
#include <hip/hip_runtime.h>

// RWKV7 attention block, MI355X/gfx950.
// B=1, T=1024, C=2048, H=32, N=64. All inputs/outputs f32.
// Big GEMMs: f16 MFMA 16x16x32, m97-style global_load_lds(16B) staging.
// LoRA stage-1: MFMA split-K, deterministic per-split partials.
// WKV scan: register-resident 8-step chunks (no LDS/barriers), DPP reductions.

#define T_ 1024
#define C_ 2048
#define H_ 32
#define N_ 64

using half8  = __attribute__((ext_vector_type(8))) _Float16;  // 8 f16 (4 VGPRs)
using half4  = __attribute__((ext_vector_type(4))) _Float16;  // 8 B
using floatx4 = __attribute__((ext_vector_type(4))) float;    // 4 f32 acc

// DPP xor-add within 16-lane rows: quad_perm(0xB1)=xor1, quad_perm(0x4E)=xor2,
// row_half_mirror(0x141)=xor4, row_mirror(0x140)=xor8.
#define DPP_ADD(v, ctrl) \
    ((v) + __int_as_float(__builtin_amdgcn_update_dpp( \
        0, __float_as_int(v), (ctrl), 0xf, 0xf, true)))
#define REDUCE16(v) do { \
    v = DPP_ADD(v, 0xB1); v = DPP_ADD(v, 0x4E); \
    v = DPP_ADD(v, 0x141); v = DPP_ADD(v, 0x140); } while (0)

// async 16B global->LDS (direct-to-LDS DMA; LDS dest = wave base + lane*16)
__device__ __forceinline__ void async_cp16(const _Float16* g, _Float16* l) {
    __builtin_amdgcn_global_load_lds(
        (const __attribute__((address_space(1))) void*)g,
        (__attribute__((address_space(3))) void*)l, 16, 0, 0);
}

// ---------------------------------------------------------------------------
// Transpose + convert big weights: W[k][n] f32 -> WT[n][k] f16
// ---------------------------------------------------------------------------
__global__ __launch_bounds__(256) void k_tr(
    const float* __restrict__ W0, const float* __restrict__ W1,
    const float* __restrict__ W2, const float* __restrict__ W3,
    _Float16* __restrict__ D0, _Float16* __restrict__ D1,
    _Float16* __restrict__ D2, _Float16* __restrict__ D3)
{
    const int z = blockIdx.z;
    const float* S = (z == 0) ? W0 : (z == 1) ? W1 : (z == 2) ? W2 : W3;
    _Float16* D = (z == 0) ? D0 : (z == 1) ? D1 : (z == 2) ? D2 : D3;
    const int nb = blockIdx.x * 64, kb = blockIdx.y * 64;
    __shared__ __align__(16) float tile[64][65];
    const int tr = threadIdx.x >> 4, tc4 = (threadIdx.x & 15) * 4;
#pragma unroll
    for (int p = 0; p < 4; ++p) {
        int row = p * 16 + tr;
        float4 v = *(const float4*)&S[(size_t)(kb + row) * C_ + nb + tc4];
        tile[row][tc4 + 0] = v.x; tile[row][tc4 + 1] = v.y;
        tile[row][tc4 + 2] = v.z; tile[row][tc4 + 3] = v.w;
    }
    __syncthreads();
#pragma unroll
    for (int p = 0; p < 4; ++p) {
        int n = p * 16 + tr;
        half4 u;
        u[0] = (_Float16)tile[tc4 + 0][n];
        u[1] = (_Float16)tile[tc4 + 1][n];
        u[2] = (_Float16)tile[tc4 + 2][n];
        u[3] = (_Float16)tile[tc4 + 3][n];
        *(half4*)&D[(size_t)(nb + n) * C_ + kb + tc4] = u;
    }
}

// ---------------------------------------------------------------------------
// Pack+transpose LoRA weights to f16 WT[n][k].
// z=0: WT_m [128][2048] <- maa_w1[2048,128]
// z=1: WT_l [256][2048] <- gate(128) | decay(64) | aaa(16) | ma(16) | kkk(16) | mk(16)
// ---------------------------------------------------------------------------
__global__ __launch_bounds__(256) void k_trW(
    const float* __restrict__ maa_w1, const float* __restrict__ gate_w1,
    const float* __restrict__ decay_w1, const float* __restrict__ aaa_w1,
    const float* __restrict__ ma_w1, const float* __restrict__ kkk_w1,
    const float* __restrict__ mk_w1,
    _Float16* __restrict__ WTm, _Float16* __restrict__ WTl)
{
    const int z = blockIdx.z;
    const int k = blockIdx.x * 256 + threadIdx.x;   // 0..2047
    const int n = blockIdx.y;
    if (z == 0 && n >= 128) return;
    const float* src; int stride, col;
    _Float16* dst;
    if (z == 0) { src = maa_w1; stride = 128; col = n; dst = WTm; }
    else {
        dst = WTl;
        if (n < 128)      { src = gate_w1;  stride = 128; col = n; }
        else if (n < 192) { src = decay_w1; stride = 64;  col = n - 128; }
        else if (n < 208) { src = aaa_w1;   stride = 16;  col = n - 192; }
        else if (n < 224) { src = ma_w1;    stride = 16;  col = n - 208; }
        else if (n < 240) { src = kkk_w1;   stride = 16;  col = n - 224; }
        else              { src = mk_w1;    stride = 16;  col = n - 240; }
    }
    dst[(size_t)n * C_ + k] = (_Float16)src[(size_t)k * stride + col];
}

// ---------------------------------------------------------------------------
// xxxH = f16( x + (x_prev - x) * maa_x )
// ---------------------------------------------------------------------------
__global__ __launch_bounds__(256) void k_prep(
    const float* __restrict__ X, const float* __restrict__ maa_x,
    _Float16* __restrict__ xxxH)
{
    const size_t idx = (size_t)blockIdx.x * 256 + threadIdx.x;
    const int c = (int)(idx & (C_ - 1));
    float cur = X[idx];
    float prev = (idx >= C_) ? X[idx - C_] : 0.0f;
    xxxH[idx] = (_Float16)(cur + (prev - cur) * maa_x[c]);
}

// ---------------------------------------------------------------------------
// LoRA MFMA GEMM, split-K -> per-split partials (deterministic; no atomics).
// BM=64, BN=32, BK=32, ksplit=4.
// which=0: m1p[ks][1024][128] = xxxH @ WTm^T (4 n-tiles)
// which=1: l2p[ks][1024][256], A per n-tile: 0-3 xrg | 4-6 xwa | 7 xk
// ---------------------------------------------------------------------------
__global__ __launch_bounds__(256) void k_lora(
    int which,
    const _Float16* __restrict__ Axxx, const _Float16* __restrict__ Axrg,
    const _Float16* __restrict__ Axwa, const _Float16* __restrict__ Axk,
    const _Float16* __restrict__ WTm, const _Float16* __restrict__ WTl,
    float* __restrict__ m1p, float* __restrict__ l2p)
{
    const int mt = blockIdx.x;      // 16 tiles of 64 rows
    const int nt = blockIdx.y;      // tiles of 32 cols
    const int ks = blockIdx.z;      // 4 K-chunks of 512
    const _Float16* A; const _Float16* BT; float* O; int ostride;
    if (which == 0) { A = Axxx; BT = WTm; O = m1p; ostride = 128; }
    else {
        BT = WTl; O = l2p; ostride = 256;
        A = (nt < 4) ? Axrg : (nt < 7) ? Axwa : Axk;
    }
    O += (size_t)ks * T_ * ostride;
    const int m0 = mt * 64, n0 = nt * 32, k0 = ks * 512;
    const int tid = threadIdx.x;
    __shared__ __align__(16) _Float16 As[64 * 40];
    __shared__ __align__(16) _Float16 Bs[32 * 40];
    const int lane = tid & 63, wv = tid >> 6;
    const int r16 = lane & 15, q = lane >> 4;

    floatx4 acc[2];
    { floatx4 zv = {0.f, 0.f, 0.f, 0.f}; acc[0] = zv; acc[1] = zv; }

    const int arow = tid >> 2, ac8 = (tid & 3) * 8;
    const _Float16* ag = A + (size_t)(m0 + arow) * C_ + k0 + ac8;
    const _Float16* bg = BT + (size_t)(n0 + (tid >> 2)) * C_ + k0 + ac8;

    for (int kc = 0; kc < 512; kc += 32) {
        half8 av = *(const half8*)(ag + kc);
        half8 bv;
        if (tid < 128) bv = *(const half8*)(bg + kc);
        *(half8*)&As[arow * 40 + ac8] = av;
        if (tid < 128) *(half8*)&Bs[(tid >> 2) * 40 + ac8] = bv;
        __syncthreads();
        half8 af = *(const half8*)&As[(wv * 16 + r16) * 40 + q * 8];
        half8 b0 = *(const half8*)&Bs[(r16) * 40 + q * 8];
        half8 b1 = *(const half8*)&Bs[(16 + r16) * 40 + q * 8];
        acc[0] = __builtin_amdgcn_mfma_f32_16x16x32_f16(af, b0, acc[0], 0, 0, 0);
        acc[1] = __builtin_amdgcn_mfma_f32_16x16x32_f16(af, b1, acc[1], 0, 0, 0);
        __syncthreads();
    }
#pragma unroll
    for (int j = 0; j < 2; ++j)
#pragma unroll
        for (int e = 0; e < 4; ++e) {
            int row = m0 + wv * 16 + q * 4 + e;
            int col = n0 + j * 16 + r16;
            O[(size_t)row * ostride + col] = acc[j][e];
        }
}

// ---------------------------------------------------------------------------
// xmix: m1 = sum_ks(m1p), tanh; mix = einsum(m1[T,4,32], maa_w2[4,32,C]);
// emit f16 GEMM operands xrgH/xwaH/xkH/xvH.
// ---------------------------------------------------------------------------
__global__ __launch_bounds__(256) void k_xmix(
    const float* __restrict__ X, const float* __restrict__ m1p,
    const float* __restrict__ w2,
    const float* __restrict__ mrg, const float* __restrict__ mwa,
    const float* __restrict__ mk, const float* __restrict__ mv,
    _Float16* __restrict__ xrgH, _Float16* __restrict__ xwaH,
    _Float16* __restrict__ xkH, _Float16* __restrict__ xvH)
{
    const int tid = threadIdx.x;
    const int c = blockIdx.x * 256 + tid;
    const int t0 = blockIdx.y * 16;
    const size_t P = (size_t)T_ * 128;
    __shared__ __align__(16) float m1s[16][128];
#pragma unroll
    for (int p = 0; p < 2; ++p) {
        int id = tid + p * 256;
        int r = id >> 5, c4 = (id & 31) * 4;
        size_t off = (size_t)(t0 + r) * 128 + c4;
        float4 v0 = *(const float4*)&m1p[off];
        float4 v1 = *(const float4*)&m1p[P + off];
        float4 v2 = *(const float4*)&m1p[2 * P + off];
        float4 v3 = *(const float4*)&m1p[3 * P + off];
        float4 v;
        v.x = tanhf(((v0.x + v1.x) + v2.x) + v3.x);
        v.y = tanhf(((v0.y + v1.y) + v2.y) + v3.y);
        v.z = tanhf(((v0.z + v1.z) + v2.z) + v3.z);
        v.w = tanhf(((v0.w + v1.w) + v2.w) + v3.w);
        *(float4*)&m1s[r][c4] = v;
    }
    __syncthreads();
    float a0[16], a1[16], a2[16], a3[16];
#pragma unroll
    for (int t = 0; t < 16; ++t) { a0[t] = 0.f; a1[t] = 0.f; a2[t] = 0.f; a3[t] = 0.f; }
    for (int d = 0; d < 32; ++d) {
        float w0 = w2[(size_t)(0 * 32 + d) * C_ + c];
        float w1 = w2[(size_t)(1 * 32 + d) * C_ + c];
        float w2v = w2[(size_t)(2 * 32 + d) * C_ + c];
        float w3 = w2[(size_t)(3 * 32 + d) * C_ + c];
#pragma unroll
        for (int t = 0; t < 16; ++t) {
            a0[t] = fmaf(m1s[t][d],      w0,  a0[t]);
            a1[t] = fmaf(m1s[t][32 + d], w1,  a1[t]);
            a2[t] = fmaf(m1s[t][64 + d], w2v, a2[t]);
            a3[t] = fmaf(m1s[t][96 + d], w3,  a3[t]);
        }
    }
    float vrg = mrg[c], vwa = mwa[c], vmk = mk[c], vmv = mv[c];
    float prev = (t0 > 0) ? X[(size_t)(t0 - 1) * C_ + c] : 0.0f;
    for (int t = 0; t < 16; ++t) {
        size_t idx = (size_t)(t0 + t) * C_ + c;
        float cur = X[idx];
        float dx = prev - cur;
        xrgH[idx] = (_Float16)(cur + dx * (vrg + a0[t]));
        xwaH[idx] = (_Float16)(cur + dx * (vwa + a1[t]));
        xkH[idx]  = (_Float16)(cur + dx * (vmk + a2[t]));
        xvH[idx]  = (_Float16)(cur + dx * (vmv + a3[t]));
        prev = cur;
    }
}

// ---------------------------------------------------------------------------
// f16 MFMA GEMM: C[1024,2048] = A(f16) @ W via WT[n][k] f16.
// BM=BN=128, BK=32, 256 thr (4 waves 2x2), 4x4 16x16x32 tiles/wave.
// m97-style: global_load_lds 16B staging, unpadded 128x32 LDS tiles.
// ---------------------------------------------------------------------------
__global__ __launch_bounds__(256) void k_gemm(
    const _Float16* __restrict__ A0, const _Float16* __restrict__ B0, float* __restrict__ C0,
    const _Float16* __restrict__ A1, const _Float16* __restrict__ B1, float* __restrict__ C1,
    const _Float16* __restrict__ A2, const _Float16* __restrict__ B2, float* __restrict__ C2)
{
    const int z = blockIdx.z;
    const _Float16* A = (z == 0) ? A0 : (z == 1) ? A1 : A2;
    const _Float16* Bt = (z == 0) ? B0 : (z == 1) ? B1 : B2;
    float* C = (z == 0) ? C0 : (z == 1) ? C1 : C2;
    const int mtile = blockIdx.y * 128;
    const int ntile = blockIdx.x * 128;
    const int tid = threadIdx.x;
    __shared__ __align__(16) _Float16 As[128 * 32];  // unpadded (async-copy layout)
    __shared__ __align__(16) _Float16 Bs[128 * 32];
    const int lane = tid & 63;
    const int wvid = tid >> 6;
    const int wm = wvid >> 1, wn = wvid & 1;
    const int r16 = lane & 15, q = lane >> 4;

    floatx4 acc[4][4];
#pragma unroll
    for (int i = 0; i < 4; ++i)
#pragma unroll
        for (int j = 0; j < 4; ++j) { floatx4 zv = {0.f, 0.f, 0.f, 0.f}; acc[i][j] = zv; }

    // staging: thread tid -> row = tid>>2 (0..63), quarter = tid&3 (16B each);
    // two calls per matrix cover rows 0-63 / 64-127. LDS is linear per wave:
    // elem offset tid*8 = lane*16B within wave -> matches HW lane scatter.
    const int srow = tid >> 2, sq = tid & 3;
    const _Float16* agA = A + (size_t)(mtile + srow) * C_ + sq * 8;
    const _Float16* agB = Bt + (size_t)(ntile + srow) * C_ + sq * 8;
    _Float16* ldsA = &As[srow * 32 + sq * 8];
    _Float16* ldsB = &Bs[srow * 32 + sq * 8];
    const size_t rowoff = (size_t)64 * C_;

    for (int kc = 0; kc < C_; kc += 32) {
        async_cp16(agA + kc, ldsA);
        async_cp16(agA + kc + rowoff, ldsA + 64 * 32);
        async_cp16(agB + kc, ldsB);
        async_cp16(agB + kc + rowoff, ldsB + 64 * 32);
        __syncthreads();

        half8 af[4], bf[4];
#pragma unroll
        for (int i = 0; i < 4; ++i)
            af[i] = *(const half8*)&As[(wm * 64 + i * 16 + r16) * 32 + q * 8];
#pragma unroll
        for (int j = 0; j < 4; ++j)
            bf[j] = *(const half8*)&Bs[(wn * 64 + j * 16 + r16) * 32 + q * 8];
#pragma unroll
        for (int i = 0; i < 4; ++i)
#pragma unroll
            for (int j = 0; j < 4; ++j)
                acc[i][j] = __builtin_amdgcn_mfma_f32_16x16x32_f16(af[i], bf[j], acc[i][j], 0, 0, 0);
        __syncthreads();
    }
    // C/D layout: col = lane&15, row = (lane>>4)*4 + reg
#pragma unroll
    for (int i = 0; i < 4; ++i)
#pragma unroll
        for (int j = 0; j < 4; ++j)
#pragma unroll
            for (int e = 0; e < 4; ++e) {
                int row = mtile + wm * 64 + i * 16 + q * 4 + e;
                int col = ntile + wn * 64 + j * 16 + r16;
                C[(size_t)row * C_ + col] = acc[i][j][e];
            }
}

// ---------------------------------------------------------------------------
// Fused stage-2: w, a, ma, mk, kk (normalized!), b = kk*a, k_final.
// l2p partials [4][T][256]: cols 128-191 decay(tanh) | 192-207 aaa |
// 208-223 ma | 224-239 kkk(tanh) | 240-255 mk. Fixed-order reduce.
// Head = 64 consecutive lanes -> in-wave L2-norm via DPP + 2 shfl.
// ---------------------------------------------------------------------------
__global__ __launch_bounds__(256) void k_fuse(
    const float* __restrict__ l2p,
    float* __restrict__ K0,
    const float* __restrict__ decay_w2, const float* __restrict__ aaa_w2,
    const float* __restrict__ ma_w2, const float* __restrict__ kkk_w2,
    const float* __restrict__ mk_w2,
    const float* __restrict__ tdecay, const float* __restrict__ aaaaa,
    const float* __restrict__ misc_a, const float* __restrict__ misc_k,
    float* __restrict__ Wout, float* __restrict__ KKout, float* __restrict__ Bout)
{
    const int tid = threadIdx.x;
    const int c = blockIdx.x * 256 + tid;
    const int t0 = blockIdx.y * 16;
    const size_t P = (size_t)T_ * 256;
    __shared__ __align__(16) float wsS[16][96];   // decay64 | aaa16 | ma16
    __shared__ __align__(16) float ksS[16][32];   // kkk16 | mk16
    for (int id = tid; id < 16 * 24; id += 256) {
        int r = id / 24, c4 = (id % 24) * 4;
        size_t off = (size_t)(t0 + r) * 256 + 128 + c4;
        float4 v0 = *(const float4*)&l2p[off];
        float4 v1 = *(const float4*)&l2p[P + off];
        float4 v2 = *(const float4*)&l2p[2 * P + off];
        float4 v3 = *(const float4*)&l2p[3 * P + off];
        float4 v;
        v.x = ((v0.x + v1.x) + v2.x) + v3.x;
        v.y = ((v0.y + v1.y) + v2.y) + v3.y;
        v.z = ((v0.z + v1.z) + v2.z) + v3.z;
        v.w = ((v0.w + v1.w) + v2.w) + v3.w;
        if (c4 < 64) { v.x = tanhf(v.x); v.y = tanhf(v.y); v.z = tanhf(v.z); v.w = tanhf(v.w); }
        *(float4*)&wsS[r][c4] = v;
    }
    for (int id = tid; id < 16 * 8; id += 256) {
        int r = id / 8, c4 = (id % 8) * 4;
        size_t off = (size_t)(t0 + r) * 256 + 224 + c4;
        float4 v0 = *(const float4*)&l2p[off];
        float4 v1 = *(const float4*)&l2p[P + off];
        float4 v2 = *(const float4*)&l2p[2 * P + off];
        float4 v3 = *(const float4*)&l2p[3 * P + off];
        float4 v;
        v.x = ((v0.x + v1.x) + v2.x) + v3.x;
        v.y = ((v0.y + v1.y) + v2.y) + v3.y;
        v.z = ((v0.z + v1.z) + v2.z) + v3.z;
        v.w = ((v0.w + v1.w) + v2.w) + v3.w;
        if (c4 < 16) { v.x = tanhf(v.x); v.y = tanhf(v.y); v.z = tanhf(v.z); v.w = tanhf(v.w); }
        *(float4*)&ksS[r][c4] = v;
    }
    __syncthreads();
    float accW[16], accA[16], accMA[16], accKK[16], accMK[16];
#pragma unroll
    for (int r = 0; r < 16; ++r) { accW[r] = 0.f; accA[r] = 0.f; accMA[r] = 0.f; accKK[r] = 0.f; accMK[r] = 0.f; }
    for (int j = 0; j < 64; ++j) {
        float w = decay_w2[(size_t)j * C_ + c];
#pragma unroll
        for (int r = 0; r < 16; ++r) accW[r] = fmaf(wsS[r][j], w, accW[r]);
    }
    for (int j = 0; j < 16; ++j) {
        float wa = aaa_w2[(size_t)j * C_ + c];
        float wm = ma_w2[(size_t)j * C_ + c];
        float wk = kkk_w2[(size_t)j * C_ + c];
        float wq = mk_w2[(size_t)j * C_ + c];
#pragma unroll
        for (int r = 0; r < 16; ++r) {
            accA[r]  = fmaf(wsS[r][64 + j], wa, accA[r]);
            accMA[r] = fmaf(wsS[r][80 + j], wm, accMA[r]);
            accKK[r] = fmaf(ksS[r][j],      wk, accKK[r]);
            accMK[r] = fmaf(ksS[r][16 + j], wq, accMK[r]);
        }
    }
    float td = tdecay[c], aa = aaaaa[c], mia = misc_a[c], mik = misc_k[c];
    for (int r = 0; r < 16; ++r) {
        size_t idx = (size_t)(t0 + r) * C_ + c;
        float wraw = td + accW[r];
        float w = -logf(1.0f + __expf(-wraw)) - 0.5f;   // -softplus(-x) - 0.5
        float a  = 1.0f / (1.0f + __expf(-(aa  + accA[r])));
        float mav = 1.0f / (1.0f + __expf(-(mia + accMA[r])));
        float mkv = 1.0f / (1.0f + __expf(-(mik + accMK[r])));
        float k0 = K0[idx];
        float kkun = k0 + accKK[r];
        // L2 norm over the head's 64 channels (= 64 consecutive lanes)
        float ss = kkun * kkun;
        REDUCE16(ss);
        ss += __shfl_xor(ss, 16, 64);
        ss += __shfl_xor(ss, 32, 64);
        float kn = kkun * (1.0f / fmaxf(sqrtf(ss), 1e-12f));
        Wout[idx]  = w;
        KKout[idx] = kn;
        Bout[idx]  = kn * a;
        K0[idx]    = k0 * (mav + a * (1.0f - mav)) * __expf(fminf(w * mkv, 0.0f));
    }
}

// ---------------------------------------------------------------------------
// WKV7 scan v3: register-resident 8-step chunks, no LDS, no barriers.
// 4 blocks/head; 256 thr; wave = 4 rows x 16 j-groups; thread owns 4 j's.
// ---------------------------------------------------------------------------
__global__ __launch_bounds__(256, 1) void k_wkv(
    const float* __restrict__ R, const float* __restrict__ Wd,
    const float* __restrict__ K, const float* __restrict__ V,
    const float* __restrict__ KK, const float* __restrict__ Bb,
    float* __restrict__ Y)
{
    const int tid = threadIdx.x;
    const int h = blockIdx.x >> 2;
    const int rg = blockIdx.x & 3;
    const int c0 = h * 64;
    const int wv = tid >> 6, lane = tid & 63;
    const int irow = rg * 16 + wv * 4 + (lane >> 4);
    const int jg = lane & 15;
    const int j4 = jg * 4;

    float4 s = make_float4(0.f, 0.f, 0.f, 0.f);

    for (int tc = 0; tc < T_; tc += 8) {
        float4 rr[8], ww[8], kq[8], aq[8], bq[8];
        float vv[8];
#pragma unroll
        for (int u = 0; u < 8; ++u) {
            const size_t base = (size_t)(tc + u) * C_ + c0;
            rr[u] = *(const float4*)&R[base + j4];
            ww[u] = *(const float4*)&Wd[base + j4];
            kq[u] = *(const float4*)&K[base + j4];
            aq[u] = *(const float4*)&KK[base + j4];   // a = -kk
            bq[u] = *(const float4*)&Bb[base + j4];
            vv[u] = V[base + irow];
        }
#pragma unroll
        for (int u = 0; u < 8; ++u) {
            float4 d;
            d.x = __expf(ww[u].x); d.y = __expf(ww[u].y);
            d.z = __expf(ww[u].z); d.w = __expf(ww[u].w);
            // sa = s . (-kk) ; negation is exact, distributes through fma
            float sa = -(s.x * aq[u].x + s.y * aq[u].y + s.z * aq[u].z + s.w * aq[u].w);
            REDUCE16(sa);
            float vi = vv[u];
            s.x = fmaf(s.x, d.x, fmaf(sa, bq[u].x, vi * kq[u].x));
            s.y = fmaf(s.y, d.y, fmaf(sa, bq[u].y, vi * kq[u].y));
            s.z = fmaf(s.z, d.z, fmaf(sa, bq[u].z, vi * kq[u].z));
            s.w = fmaf(s.w, d.w, fmaf(sa, bq[u].w, vi * kq[u].w));
            float o = s.x * rr[u].x + s.y * rr[u].y + s.z * rr[u].z + s.w * rr[u].w;
            REDUCE16(o);
            if (jg == 0) Y[(size_t)(tc + u) * C_ + c0 + irow] = o;
        }
    }
}

// ---------------------------------------------------------------------------
// GroupNorm(y)*ln_w+ln_b, + bonus, * gate(fused: tanh(l2 sum) @ gate_w2)
// -> f16 A-operand of the Wo GEMM.
// ---------------------------------------------------------------------------
__global__ __launch_bounds__(256) void k_gn(
    const float* __restrict__ Y, const float* __restrict__ R, const float* __restrict__ K,
    const float* __restrict__ V, const float* __restrict__ l2p,
    const float* __restrict__ gw2,
    const float* __restrict__ faaaa, const float* __restrict__ lnw,
    const float* __restrict__ lnb, _Float16* __restrict__ YG)
{
    const int t = blockIdx.y;
    const int c = blockIdx.x * 256 + threadIdx.x;
    const size_t idx = (size_t)t * C_ + c;
    __shared__ __align__(16) float gs[128];
    if (threadIdx.x < 128) {
        const size_t P = (size_t)T_ * 256;
        size_t off = (size_t)t * 256 + threadIdx.x;
        float v = ((l2p[off] + l2p[P + off]) + l2p[2 * P + off]) + l2p[3 * P + off];
        gs[threadIdx.x] = tanhf(v);
    }
    __syncthreads();
    float y = Y[idx];
    float s1 = y, s2 = y * y;
#pragma unroll
    for (int off = 1; off < 64; off <<= 1) {
        s1 += __shfl_xor(s1, off, 64);
        s2 += __shfl_xor(s2, off, 64);
    }
    float mu = s1 * (1.0f / 64.0f);
    float var = s2 * (1.0f / 64.0f) - mu * mu;
    float gn = (y - mu) * rsqrtf(var + 0.00064f) * lnw[c] + lnb[c];
    float p = R[idx] * K[idx] * faaaa[c];
#pragma unroll
    for (int off = 1; off < 64; off <<= 1) p += __shfl_xor(p, off, 64);
    float y2 = gn + p * V[idx];
    float g = 0.f;
    for (int j = 0; j < 128; ++j) g = fmaf(gs[j], gw2[(size_t)j * C_ + c], g);
    YG[idx] = (_Float16)(y2 * g);
}

// ---------------------------------------------------------------------------
extern "C" void kernel_launch(void* const* d_in, const int* in_sizes, int n_in,
                              void* d_out, int out_size, void* d_ws, size_t ws_size,
                              hipStream_t stream)
{
    (void)in_sizes; (void)n_in; (void)out_size; (void)ws_size;
    const float* hidden   = (const float*)d_in[0];
    const float* Wq       = (const float*)d_in[1];
    const float* Wk       = (const float*)d_in[2];
    const float* Wv       = (const float*)d_in[3];
    const float* Wo       = (const float*)d_in[4];
    const float* maa_x    = (const float*)d_in[5];
    const float* maa_rg   = (const float*)d_in[6];
    const float* maa_wa   = (const float*)d_in[7];
    const float* maa_k    = (const float*)d_in[8];
    const float* maa_v    = (const float*)d_in[9];
    const float* maa_w1   = (const float*)d_in[10];
    const float* maa_w2   = (const float*)d_in[11];
    const float* tdecay   = (const float*)d_in[12];
    const float* decay_w1 = (const float*)d_in[13];
    const float* decay_w2 = (const float*)d_in[14];
    const float* aaaaa    = (const float*)d_in[15];
    const float* aaa_w1   = (const float*)d_in[16];
    const float* aaa_w2   = (const float*)d_in[17];
    const float* kkk_w1   = (const float*)d_in[18];
    const float* kkk_w2   = (const float*)d_in[19];
    const float* gate_w1  = (const float*)d_in[20];
    const float* gate_w2  = (const float*)d_in[21];
    const float* misc_a   = (const float*)d_in[22];
    const float* ma_w1    = (const float*)d_in[23];
    const float* ma_w2    = (const float*)d_in[24];
    const float* misc_k   = (const float*)d_in[25];
    const float* mk_w1    = (const float*)d_in[26];
    const float* mk_w2    = (const float*)d_in[27];
    const float* faaaa    = (const float*)d_in[28];
    const float* lnw      = (const float*)d_in[29];
    const float* lnb      = (const float*)d_in[30];

    float* ws = (float*)d_ws;
    const size_t TC = (size_t)T_ * C_;
    // f32 buffers:
    //   S0: y   S2: b   S3: kk   S4: r   S5: w   S6: k0 -> k   S7: v
    float* S0 = ws + 0 * TC;
    float* S2 = ws + 2 * TC;
    float* S3 = ws + 3 * TC;
    float* S4 = ws + 4 * TC;
    float* S5 = ws + 5 * TC;
    float* S6 = ws + 6 * TC;
    float* S7 = ws + 7 * TC;
    float* m1p = ws + 8 * TC;                    // [4][T][128] partials
    float* l2p = m1p + (size_t)4 * T_ * 128;     // [4][T][256] partials
    // f16 region
    _Float16* WTq = (_Float16*)(l2p + (size_t)4 * T_ * 256);
    _Float16* WTk = WTq + (size_t)C_ * C_;
    _Float16* WTv = WTk + (size_t)C_ * C_;
    _Float16* WTo = WTv + (size_t)C_ * C_;
    _Float16* WTm = WTo + (size_t)C_ * C_;       // [128,2048]
    _Float16* WTl = WTm + (size_t)128 * C_;      // [256,2048]
    _Float16* xxxH = WTl + (size_t)256 * C_;
    _Float16* xrgH = xxxH + TC;
    _Float16* xwaH = xrgH + TC;
    _Float16* xkH  = xwaH + TC;
    _Float16* xvH  = xkH + TC;
    _Float16* ygH  = xxxH;                       // xxxH dead after step 6
    float* out = (float*)d_out;

    // 1. transpose+convert big weights
    k_tr<<<dim3(32, 32, 4), 256, 0, stream>>>(Wq, Wk, Wv, Wo, WTq, WTk, WTv, WTo);
    // 2. pack+transpose LoRA weights (z=0: WTm, z=1: WTl)
    k_trW<<<dim3(8, 256, 2), 256, 0, stream>>>(maa_w1, gate_w1, decay_w1,
        aaa_w1, ma_w1, kkk_w1, mk_w1, WTm, WTl);
    // 3. xxxH
    k_prep<<<dim3((int)(TC / 256)), 256, 0, stream>>>(hidden, maa_x, xxxH);
    // 4. m1 partials = xxxH @ WTm^T
    k_lora<<<dim3(16, 4, 4), 256, 0, stream>>>(0, xxxH, xxxH, xxxH, xxxH,
        WTm, WTl, m1p, l2p);
    // 5. xmix -> f16 operands
    k_xmix<<<dim3(8, 64), 256, 0, stream>>>(hidden, m1p, maa_w2,
        maa_rg, maa_wa, maa_k, maa_v, xrgH, xwaH, xkH, xvH);
    // 6. l2 partials (gate | decay | aaa | ma | kkk | mk)
    k_lora<<<dim3(16, 8, 4), 256, 0, stream>>>(1, xxxH, xrgH, xwaH, xkH,
        WTm, WTl, m1p, l2p);
    // 7. r, k0, v (f16 MFMA, async staging)
    k_gemm<<<dim3(16, 8, 3), 256, 0, stream>>>(
        xrgH, WTq, S4,  xkH, WTk, S6,  xvH, WTv, S7);
    // 8. fused stage-2: w, kk (normalized), b, k_final
    k_fuse<<<dim3(8, 64), 256, 0, stream>>>(l2p, S6, decay_w2, aaa_w2, ma_w2,
        kkk_w2, mk_w2, tdecay, aaaaa, misc_a, misc_k, S5, S3, S2);
    // 9. WKV7 scan -> y (S0)
    k_wkv<<<dim3(128), 256, 0, stream>>>(S4, S5, S6, S7, S3, S2, S0);
    // 10. groupnorm + bonus + fused gate -> f16 (reuses xxxH slot)
    k_gn<<<dim3(8, 1024), 256, 0, stream>>>(S0, S4, S6, S7, l2p, gate_w2,
        faaaa, lnw, lnb, ygH);
    // 11. out = (y*g) @ Wo
    k_gemm<<<dim3(16, 8, 1), 256, 0, stream>>>(
        ygH, WTo, out,  ygH, WTo, out,  ygH, WTo, out);
}

// Round 7
// 605.901 us; speedup vs baseline: 1.0796x; 1.0796x over previous
//
#include <hip/hip_runtime.h>

// RWKV7 attention block, MI355X/gfx950.
// B=1, T=1024, C=2048, H=32, N=64. All inputs/outputs f32.
// Big GEMMs: f16 MFMA 16x16x32, double-buffered global_load_lds(16B) staging.
// LoRA stage-1: MFMA split-K, deterministic per-split partials.
// WKV scan: double-buffered async LDS chunks (dec precomputed), DPP reductions.

#define T_ 1024
#define C_ 2048
#define H_ 32
#define N_ 64

using half8  = __attribute__((ext_vector_type(8))) _Float16;  // 8 f16 (4 VGPRs)
using half4  = __attribute__((ext_vector_type(4))) _Float16;  // 8 B
using floatx4 = __attribute__((ext_vector_type(4))) float;    // 4 f32 acc

// DPP xor-add within 16-lane rows: quad_perm(0xB1)=xor1, quad_perm(0x4E)=xor2,
// row_half_mirror(0x141)=xor4, row_mirror(0x140)=xor8.
#define DPP_ADD(v, ctrl) \
    ((v) + __int_as_float(__builtin_amdgcn_update_dpp( \
        0, __float_as_int(v), (ctrl), 0xf, 0xf, true)))
#define REDUCE16(v) do { \
    v = DPP_ADD(v, 0xB1); v = DPP_ADD(v, 0x4E); \
    v = DPP_ADD(v, 0x141); v = DPP_ADD(v, 0x140); } while (0)

// async 16B global->LDS (direct-to-LDS DMA; HW dest = wave base + lane*16,
// our per-lane lds ptrs are constructed to match exactly that layout)
__device__ __forceinline__ void async_cp16(const void* g, void* l) {
    __builtin_amdgcn_global_load_lds(
        (const __attribute__((address_space(1))) void*)g,
        (__attribute__((address_space(3))) void*)l, 16, 0, 0);
}

// ---------------------------------------------------------------------------
// Transpose + convert big weights: W[k][n] f32 -> WT[n][k] f16
// ---------------------------------------------------------------------------
__global__ __launch_bounds__(256) void k_tr(
    const float* __restrict__ W0, const float* __restrict__ W1,
    const float* __restrict__ W2, const float* __restrict__ W3,
    _Float16* __restrict__ D0, _Float16* __restrict__ D1,
    _Float16* __restrict__ D2, _Float16* __restrict__ D3)
{
    const int z = blockIdx.z;
    const float* S = (z == 0) ? W0 : (z == 1) ? W1 : (z == 2) ? W2 : W3;
    _Float16* D = (z == 0) ? D0 : (z == 1) ? D1 : (z == 2) ? D2 : D3;
    const int nb = blockIdx.x * 64, kb = blockIdx.y * 64;
    __shared__ __align__(16) float tile[64][65];
    const int tr = threadIdx.x >> 4, tc4 = (threadIdx.x & 15) * 4;
#pragma unroll
    for (int p = 0; p < 4; ++p) {
        int row = p * 16 + tr;
        float4 v = *(const float4*)&S[(size_t)(kb + row) * C_ + nb + tc4];
        tile[row][tc4 + 0] = v.x; tile[row][tc4 + 1] = v.y;
        tile[row][tc4 + 2] = v.z; tile[row][tc4 + 3] = v.w;
    }
    __syncthreads();
#pragma unroll
    for (int p = 0; p < 4; ++p) {
        int n = p * 16 + tr;
        half4 u;
        u[0] = (_Float16)tile[tc4 + 0][n];
        u[1] = (_Float16)tile[tc4 + 1][n];
        u[2] = (_Float16)tile[tc4 + 2][n];
        u[3] = (_Float16)tile[tc4 + 3][n];
        *(half4*)&D[(size_t)(nb + n) * C_ + kb + tc4] = u;
    }
}

// ---------------------------------------------------------------------------
// Pack+transpose LoRA weights to f16 WT[n][k].
// z=0: WT_m [128][2048] <- maa_w1[2048,128]
// z=1: WT_l [256][2048] <- gate(128) | decay(64) | aaa(16) | ma(16) | kkk(16) | mk(16)
// ---------------------------------------------------------------------------
__global__ __launch_bounds__(256) void k_trW(
    const float* __restrict__ maa_w1, const float* __restrict__ gate_w1,
    const float* __restrict__ decay_w1, const float* __restrict__ aaa_w1,
    const float* __restrict__ ma_w1, const float* __restrict__ kkk_w1,
    const float* __restrict__ mk_w1,
    _Float16* __restrict__ WTm, _Float16* __restrict__ WTl)
{
    const int z = blockIdx.z;
    const int k = blockIdx.x * 256 + threadIdx.x;   // 0..2047
    const int n = blockIdx.y;
    if (z == 0 && n >= 128) return;
    const float* src; int stride, col;
    _Float16* dst;
    if (z == 0) { src = maa_w1; stride = 128; col = n; dst = WTm; }
    else {
        dst = WTl;
        if (n < 128)      { src = gate_w1;  stride = 128; col = n; }
        else if (n < 192) { src = decay_w1; stride = 64;  col = n - 128; }
        else if (n < 208) { src = aaa_w1;   stride = 16;  col = n - 192; }
        else if (n < 224) { src = ma_w1;    stride = 16;  col = n - 208; }
        else if (n < 240) { src = kkk_w1;   stride = 16;  col = n - 224; }
        else              { src = mk_w1;    stride = 16;  col = n - 240; }
    }
    dst[(size_t)n * C_ + k] = (_Float16)src[(size_t)k * stride + col];
}

// ---------------------------------------------------------------------------
// xxxH = f16( x + (x_prev - x) * maa_x )
// ---------------------------------------------------------------------------
__global__ __launch_bounds__(256) void k_prep(
    const float* __restrict__ X, const float* __restrict__ maa_x,
    _Float16* __restrict__ xxxH)
{
    const size_t idx = (size_t)blockIdx.x * 256 + threadIdx.x;
    const int c = (int)(idx & (C_ - 1));
    float cur = X[idx];
    float prev = (idx >= C_) ? X[idx - C_] : 0.0f;
    xxxH[idx] = (_Float16)(cur + (prev - cur) * maa_x[c]);
}

// ---------------------------------------------------------------------------
// LoRA MFMA GEMM, split-K -> per-split partials (deterministic; no atomics).
// BM=64, BN=32, BK=32, ksplit=4.
// which=0: m1p[ks][1024][128] = xxxH @ WTm^T (4 n-tiles)
// which=1: l2p[ks][1024][256], A per n-tile: 0-3 xrg | 4-6 xwa | 7 xk
// ---------------------------------------------------------------------------
__global__ __launch_bounds__(256) void k_lora(
    int which,
    const _Float16* __restrict__ Axxx, const _Float16* __restrict__ Axrg,
    const _Float16* __restrict__ Axwa, const _Float16* __restrict__ Axk,
    const _Float16* __restrict__ WTm, const _Float16* __restrict__ WTl,
    float* __restrict__ m1p, float* __restrict__ l2p)
{
    const int mt = blockIdx.x;      // 16 tiles of 64 rows
    const int nt = blockIdx.y;      // tiles of 32 cols
    const int ks = blockIdx.z;      // 4 K-chunks of 512
    const _Float16* A; const _Float16* BT; float* O; int ostride;
    if (which == 0) { A = Axxx; BT = WTm; O = m1p; ostride = 128; }
    else {
        BT = WTl; O = l2p; ostride = 256;
        A = (nt < 4) ? Axrg : (nt < 7) ? Axwa : Axk;
    }
    O += (size_t)ks * T_ * ostride;
    const int m0 = mt * 64, n0 = nt * 32, k0 = ks * 512;
    const int tid = threadIdx.x;
    __shared__ __align__(16) _Float16 As[64 * 40];
    __shared__ __align__(16) _Float16 Bs[32 * 40];
    const int lane = tid & 63, wv = tid >> 6;
    const int r16 = lane & 15, q = lane >> 4;

    floatx4 acc[2];
    { floatx4 zv = {0.f, 0.f, 0.f, 0.f}; acc[0] = zv; acc[1] = zv; }

    const int arow = tid >> 2, ac8 = (tid & 3) * 8;
    const _Float16* ag = A + (size_t)(m0 + arow) * C_ + k0 + ac8;
    const _Float16* bg = BT + (size_t)(n0 + (tid >> 2)) * C_ + k0 + ac8;

    for (int kc = 0; kc < 512; kc += 32) {
        half8 av = *(const half8*)(ag + kc);
        half8 bv;
        if (tid < 128) bv = *(const half8*)(bg + kc);
        *(half8*)&As[arow * 40 + ac8] = av;
        if (tid < 128) *(half8*)&Bs[(tid >> 2) * 40 + ac8] = bv;
        __syncthreads();
        half8 af = *(const half8*)&As[(wv * 16 + r16) * 40 + q * 8];
        half8 b0 = *(const half8*)&Bs[(r16) * 40 + q * 8];
        half8 b1 = *(const half8*)&Bs[(16 + r16) * 40 + q * 8];
        acc[0] = __builtin_amdgcn_mfma_f32_16x16x32_f16(af, b0, acc[0], 0, 0, 0);
        acc[1] = __builtin_amdgcn_mfma_f32_16x16x32_f16(af, b1, acc[1], 0, 0, 0);
        __syncthreads();
    }
#pragma unroll
    for (int j = 0; j < 2; ++j)
#pragma unroll
        for (int e = 0; e < 4; ++e) {
            int row = m0 + wv * 16 + q * 4 + e;
            int col = n0 + j * 16 + r16;
            O[(size_t)row * ostride + col] = acc[j][e];
        }
}

// ---------------------------------------------------------------------------
// xmix: m1 = sum_ks(m1p), tanh; mix = einsum(m1[T,4,32], maa_w2[4,32,C]);
// emit f16 GEMM operands xrgH/xwaH/xkH/xvH.
// ---------------------------------------------------------------------------
__global__ __launch_bounds__(256) void k_xmix(
    const float* __restrict__ X, const float* __restrict__ m1p,
    const float* __restrict__ w2,
    const float* __restrict__ mrg, const float* __restrict__ mwa,
    const float* __restrict__ mk, const float* __restrict__ mv,
    _Float16* __restrict__ xrgH, _Float16* __restrict__ xwaH,
    _Float16* __restrict__ xkH, _Float16* __restrict__ xvH)
{
    const int tid = threadIdx.x;
    const int c = blockIdx.x * 256 + tid;
    const int t0 = blockIdx.y * 16;
    const size_t P = (size_t)T_ * 128;
    __shared__ __align__(16) float m1s[16][128];
#pragma unroll
    for (int p = 0; p < 2; ++p) {
        int id = tid + p * 256;
        int r = id >> 5, c4 = (id & 31) * 4;
        size_t off = (size_t)(t0 + r) * 128 + c4;
        float4 v0 = *(const float4*)&m1p[off];
        float4 v1 = *(const float4*)&m1p[P + off];
        float4 v2 = *(const float4*)&m1p[2 * P + off];
        float4 v3 = *(const float4*)&m1p[3 * P + off];
        float4 v;
        v.x = tanhf(((v0.x + v1.x) + v2.x) + v3.x);
        v.y = tanhf(((v0.y + v1.y) + v2.y) + v3.y);
        v.z = tanhf(((v0.z + v1.z) + v2.z) + v3.z);
        v.w = tanhf(((v0.w + v1.w) + v2.w) + v3.w);
        *(float4*)&m1s[r][c4] = v;
    }
    __syncthreads();
    float a0[16], a1[16], a2[16], a3[16];
#pragma unroll
    for (int t = 0; t < 16; ++t) { a0[t] = 0.f; a1[t] = 0.f; a2[t] = 0.f; a3[t] = 0.f; }
    for (int d = 0; d < 32; ++d) {
        float w0 = w2[(size_t)(0 * 32 + d) * C_ + c];
        float w1 = w2[(size_t)(1 * 32 + d) * C_ + c];
        float w2v = w2[(size_t)(2 * 32 + d) * C_ + c];
        float w3 = w2[(size_t)(3 * 32 + d) * C_ + c];
#pragma unroll
        for (int t = 0; t < 16; ++t) {
            a0[t] = fmaf(m1s[t][d],      w0,  a0[t]);
            a1[t] = fmaf(m1s[t][32 + d], w1,  a1[t]);
            a2[t] = fmaf(m1s[t][64 + d], w2v, a2[t]);
            a3[t] = fmaf(m1s[t][96 + d], w3,  a3[t]);
        }
    }
    float vrg = mrg[c], vwa = mwa[c], vmk = mk[c], vmv = mv[c];
    float prev = (t0 > 0) ? X[(size_t)(t0 - 1) * C_ + c] : 0.0f;
    for (int t = 0; t < 16; ++t) {
        size_t idx = (size_t)(t0 + t) * C_ + c;
        float cur = X[idx];
        float dx = prev - cur;
        xrgH[idx] = (_Float16)(cur + dx * (vrg + a0[t]));
        xwaH[idx] = (_Float16)(cur + dx * (vwa + a1[t]));
        xkH[idx]  = (_Float16)(cur + dx * (vmk + a2[t]));
        xvH[idx]  = (_Float16)(cur + dx * (vmv + a3[t]));
        prev = cur;
    }
}

// ---------------------------------------------------------------------------
// f16 MFMA GEMM: C[1024,2048] = A(f16) @ W via WT[n][k] f16.
// BM=BN=128, BK=32, 256 thr (4 waves 2x2), 4x4 16x16x32 tiles/wave.
// Double-buffered global_load_lds staging: barrier at loop top, prefetch
// k+1 right after it, compute k — copy latency hides under compute.
// ---------------------------------------------------------------------------
__global__ __launch_bounds__(256) void k_gemm(
    const _Float16* __restrict__ A0, const _Float16* __restrict__ B0, float* __restrict__ C0,
    const _Float16* __restrict__ A1, const _Float16* __restrict__ B1, float* __restrict__ C1,
    const _Float16* __restrict__ A2, const _Float16* __restrict__ B2, float* __restrict__ C2)
{
    const int z = blockIdx.z;
    const _Float16* A = (z == 0) ? A0 : (z == 1) ? A1 : A2;
    const _Float16* Bt = (z == 0) ? B0 : (z == 1) ? B1 : B2;
    float* C = (z == 0) ? C0 : (z == 1) ? C1 : C2;
    const int mtile = blockIdx.y * 128;
    const int ntile = blockIdx.x * 128;
    const int tid = threadIdx.x;
    __shared__ __align__(16) _Float16 As[2][128 * 32];  // unpadded (async layout)
    __shared__ __align__(16) _Float16 Bs[2][128 * 32];
    const int lane = tid & 63;
    const int wvid = tid >> 6;
    const int wm = wvid >> 1, wn = wvid & 1;
    const int r16 = lane & 15, q = lane >> 4;

    floatx4 acc[4][4];
#pragma unroll
    for (int i = 0; i < 4; ++i)
#pragma unroll
        for (int j = 0; j < 4; ++j) { floatx4 zv = {0.f, 0.f, 0.f, 0.f}; acc[i][j] = zv; }

    // staging: thread -> row tid>>2 (0..63), quarter tid&3 (16B); 2 calls per
    // matrix cover rows 0-63 / 64-127. LDS dest offset = tid*16B (lane-linear).
    const int srow = tid >> 2, sq = tid & 3;
    const _Float16* agA = A + (size_t)(mtile + srow) * C_ + sq * 8;
    const _Float16* agB = Bt + (size_t)(ntile + srow) * C_ + sq * 8;
    const int ldso = srow * 32 + sq * 8;
    const size_t rowoff = (size_t)64 * C_;

    // prefetch k-chunk 0 into buf 0
    async_cp16(agA, &As[0][ldso]);
    async_cp16(agA + rowoff, &As[0][ldso + 64 * 32]);
    async_cp16(agB, &Bs[0][ldso]);
    async_cp16(agB + rowoff, &Bs[0][ldso + 64 * 32]);

    for (int kc = 0; kc < C_; kc += 32) {
        const int p = (kc >> 5) & 1;
        __syncthreads();                      // buf p ready (drains copies)
        if (kc + 32 < C_) {                   // prefetch k+1 into buf p^1
            async_cp16(agA + kc + 32, &As[p ^ 1][ldso]);
            async_cp16(agA + kc + 32 + rowoff, &As[p ^ 1][ldso + 64 * 32]);
            async_cp16(agB + kc + 32, &Bs[p ^ 1][ldso]);
            async_cp16(agB + kc + 32 + rowoff, &Bs[p ^ 1][ldso + 64 * 32]);
        }
        half8 af[4], bf[4];
#pragma unroll
        for (int i = 0; i < 4; ++i)
            af[i] = *(const half8*)&As[p][(wm * 64 + i * 16 + r16) * 32 + q * 8];
#pragma unroll
        for (int j = 0; j < 4; ++j)
            bf[j] = *(const half8*)&Bs[p][(wn * 64 + j * 16 + r16) * 32 + q * 8];
#pragma unroll
        for (int i = 0; i < 4; ++i)
#pragma unroll
            for (int j = 0; j < 4; ++j)
                acc[i][j] = __builtin_amdgcn_mfma_f32_16x16x32_f16(af[i], bf[j], acc[i][j], 0, 0, 0);
    }
    // C/D layout: col = lane&15, row = (lane>>4)*4 + reg
#pragma unroll
    for (int i = 0; i < 4; ++i)
#pragma unroll
        for (int j = 0; j < 4; ++j)
#pragma unroll
            for (int e = 0; e < 4; ++e) {
                int row = mtile + wm * 64 + i * 16 + q * 4 + e;
                int col = ntile + wn * 64 + j * 16 + r16;
                C[(size_t)row * C_ + col] = acc[i][j][e];
            }
}

// ---------------------------------------------------------------------------
// Fused stage-2: dec=exp(w), kk (normalized), b = kk*a, k_final.
// l2p partials [4][T][256]: cols 128-191 decay(tanh) | 192-207 aaa |
// 208-223 ma | 224-239 kkk(tanh) | 240-255 mk. Fixed-order reduce.
// Head = 64 consecutive lanes -> in-wave L2-norm via DPP + 2 shfl.
// ---------------------------------------------------------------------------
__global__ __launch_bounds__(256) void k_fuse(
    const float* __restrict__ l2p,
    float* __restrict__ K0,
    const float* __restrict__ decay_w2, const float* __restrict__ aaa_w2,
    const float* __restrict__ ma_w2, const float* __restrict__ kkk_w2,
    const float* __restrict__ mk_w2,
    const float* __restrict__ tdecay, const float* __restrict__ aaaaa,
    const float* __restrict__ misc_a, const float* __restrict__ misc_k,
    float* __restrict__ Dout, float* __restrict__ KKout, float* __restrict__ Bout)
{
    const int tid = threadIdx.x;
    const int c = blockIdx.x * 256 + tid;
    const int t0 = blockIdx.y * 16;
    const size_t P = (size_t)T_ * 256;
    __shared__ __align__(16) float wsS[16][96];   // decay64 | aaa16 | ma16
    __shared__ __align__(16) float ksS[16][32];   // kkk16 | mk16
    for (int id = tid; id < 16 * 24; id += 256) {
        int r = id / 24, c4 = (id % 24) * 4;
        size_t off = (size_t)(t0 + r) * 256 + 128 + c4;
        float4 v0 = *(const float4*)&l2p[off];
        float4 v1 = *(const float4*)&l2p[P + off];
        float4 v2 = *(const float4*)&l2p[2 * P + off];
        float4 v3 = *(const float4*)&l2p[3 * P + off];
        float4 v;
        v.x = ((v0.x + v1.x) + v2.x) + v3.x;
        v.y = ((v0.y + v1.y) + v2.y) + v3.y;
        v.z = ((v0.z + v1.z) + v2.z) + v3.z;
        v.w = ((v0.w + v1.w) + v2.w) + v3.w;
        if (c4 < 64) { v.x = tanhf(v.x); v.y = tanhf(v.y); v.z = tanhf(v.z); v.w = tanhf(v.w); }
        *(float4*)&wsS[r][c4] = v;
    }
    for (int id = tid; id < 16 * 8; id += 256) {
        int r = id / 8, c4 = (id % 8) * 4;
        size_t off = (size_t)(t0 + r) * 256 + 224 + c4;
        float4 v0 = *(const float4*)&l2p[off];
        float4 v1 = *(const float4*)&l2p[P + off];
        float4 v2 = *(const float4*)&l2p[2 * P + off];
        float4 v3 = *(const float4*)&l2p[3 * P + off];
        float4 v;
        v.x = ((v0.x + v1.x) + v2.x) + v3.x;
        v.y = ((v0.y + v1.y) + v2.y) + v3.y;
        v.z = ((v0.z + v1.z) + v2.z) + v3.z;
        v.w = ((v0.w + v1.w) + v2.w) + v3.w;
        if (c4 < 16) { v.x = tanhf(v.x); v.y = tanhf(v.y); v.z = tanhf(v.z); v.w = tanhf(v.w); }
        *(float4*)&ksS[r][c4] = v;
    }
    __syncthreads();
    float accW[16], accA[16], accMA[16], accKK[16], accMK[16];
#pragma unroll
    for (int r = 0; r < 16; ++r) { accW[r] = 0.f; accA[r] = 0.f; accMA[r] = 0.f; accKK[r] = 0.f; accMK[r] = 0.f; }
    for (int j = 0; j < 64; ++j) {
        float w = decay_w2[(size_t)j * C_ + c];
#pragma unroll
        for (int r = 0; r < 16; ++r) accW[r] = fmaf(wsS[r][j], w, accW[r]);
    }
    for (int j = 0; j < 16; ++j) {
        float wa = aaa_w2[(size_t)j * C_ + c];
        float wm = ma_w2[(size_t)j * C_ + c];
        float wk = kkk_w2[(size_t)j * C_ + c];
        float wq = mk_w2[(size_t)j * C_ + c];
#pragma unroll
        for (int r = 0; r < 16; ++r) {
            accA[r]  = fmaf(wsS[r][64 + j], wa, accA[r]);
            accMA[r] = fmaf(wsS[r][80 + j], wm, accMA[r]);
            accKK[r] = fmaf(ksS[r][j],      wk, accKK[r]);
            accMK[r] = fmaf(ksS[r][16 + j], wq, accMK[r]);
        }
    }
    float td = tdecay[c], aa = aaaaa[c], mia = misc_a[c], mik = misc_k[c];
    for (int r = 0; r < 16; ++r) {
        size_t idx = (size_t)(t0 + r) * C_ + c;
        float wraw = td + accW[r];
        float w = -logf(1.0f + __expf(-wraw)) - 0.5f;   // -softplus(-x) - 0.5
        float a  = 1.0f / (1.0f + __expf(-(aa  + accA[r])));
        float mav = 1.0f / (1.0f + __expf(-(mia + accMA[r])));
        float mkv = 1.0f / (1.0f + __expf(-(mik + accMK[r])));
        float k0 = K0[idx];
        float kkun = k0 + accKK[r];
        // L2 norm over the head's 64 channels (= 64 consecutive lanes)
        float ss = kkun * kkun;
        REDUCE16(ss);
        ss += __shfl_xor(ss, 16, 64);
        ss += __shfl_xor(ss, 32, 64);
        float kn = kkun * (1.0f / fmaxf(sqrtf(ss), 1e-12f));
        Dout[idx]  = __expf(w);                 // dec, precomputed for the scan
        KKout[idx] = kn;
        Bout[idx]  = kn * a;
        K0[idx]    = k0 * (mav + a * (1.0f - mav)) * __expf(fminf(w * mkv, 0.0f));
    }
}

// ---------------------------------------------------------------------------
// WKV7 scan v4: double-buffered async LDS chunks (16 steps), barrier at loop
// top + prefetch after it — copy latency hides under the chunk's compute.
// 4 blocks/head; 256 thr; wave = 4 rows x 16 j-groups; DPP reductions.
// ---------------------------------------------------------------------------
__global__ __launch_bounds__(256) void k_wkv(
    const float* __restrict__ R, const float* __restrict__ DEC,
    const float* __restrict__ K, const float* __restrict__ V,
    const float* __restrict__ KK, const float* __restrict__ Bb,
    float* __restrict__ Y)
{
    const int tid = threadIdx.x;
    const int h = blockIdx.x >> 2;
    const int rg = blockIdx.x & 3;
    const int c0 = h * 64;
    const int wv = tid >> 6, lane = tid & 63;
    const int irow = rg * 16 + wv * 4 + (lane >> 4);   // this lane's state row
    const int jg = lane & 15, j4 = jg * 4;

    // staged j-vector arrays [buf][chunk-step][64]; dest offset = lane*16B/wave
    __shared__ __align__(16) float rS[2][16][64], dS[2][16][64], kS[2][16][64],
                                   aS[2][16][64], bS[2][16][64];
    __shared__ __align__(16) float vS[2][16][16];      // block's own 16 rows

    const int tloc = wv * 4 + (lane >> 4);             // staging step 0..15
    const int sj = (lane & 15) * 4;
    const int vrow = tid >> 2, vc4 = (tid & 3) * 4;    // v staging (wave 0)

    // prefetch chunk 0 into buf 0
    {
        size_t g = (size_t)tloc * C_ + c0 + sj;
        async_cp16(&R[g],   &rS[0][tloc][sj]);
        async_cp16(&DEC[g], &dS[0][tloc][sj]);
        async_cp16(&K[g],   &kS[0][tloc][sj]);
        async_cp16(&KK[g],  &aS[0][tloc][sj]);
        async_cp16(&Bb[g],  &bS[0][tloc][sj]);
        if (wv == 0)
            async_cp16(&V[(size_t)vrow * C_ + c0 + rg * 16 + vc4], &vS[0][vrow][vc4]);
    }

    float4 s = make_float4(0.f, 0.f, 0.f, 0.f);

    for (int tc = 0; tc < T_; tc += 16) {
        const int p = (tc >> 4) & 1;
        __syncthreads();                               // buf p ready
        if (tc + 16 < T_) {                            // prefetch next chunk
            size_t g = (size_t)(tc + 16 + tloc) * C_ + c0 + sj;
            async_cp16(&R[g],   &rS[p ^ 1][tloc][sj]);
            async_cp16(&DEC[g], &dS[p ^ 1][tloc][sj]);
            async_cp16(&K[g],   &kS[p ^ 1][tloc][sj]);
            async_cp16(&KK[g],  &aS[p ^ 1][tloc][sj]);
            async_cp16(&Bb[g],  &bS[p ^ 1][tloc][sj]);
            if (wv == 0)
                async_cp16(&V[(size_t)(tc + 16 + vrow) * C_ + c0 + rg * 16 + vc4],
                           &vS[p ^ 1][vrow][vc4]);
        }
#pragma unroll
        for (int tt = 0; tt < 16; ++tt) {
            float4 kk = *(float4*)&aS[p][tt][j4];
            float sa = -(s.x * kk.x + s.y * kk.y + s.z * kk.z + s.w * kk.w);
            REDUCE16(sa);
            float4 d = *(float4*)&dS[p][tt][j4];
            float4 b = *(float4*)&bS[p][tt][j4];
            float4 k = *(float4*)&kS[p][tt][j4];
            float vi = vS[p][tt][wv * 4 + (lane >> 4)];
            s.x = fmaf(s.x, d.x, fmaf(sa, b.x, vi * k.x));
            s.y = fmaf(s.y, d.y, fmaf(sa, b.y, vi * k.y));
            s.z = fmaf(s.z, d.z, fmaf(sa, b.z, vi * k.z));
            s.w = fmaf(s.w, d.w, fmaf(sa, b.w, vi * k.w));
            float4 r = *(float4*)&rS[p][tt][j4];
            float o = s.x * r.x + s.y * r.y + s.z * r.z + s.w * r.w;
            REDUCE16(o);
            if (jg == 0) Y[(size_t)(tc + tt) * C_ + c0 + irow] = o;
        }
    }
}

// ---------------------------------------------------------------------------
// GroupNorm(y)*ln_w+ln_b, + bonus, * gate(fused: tanh(l2 sum) @ gate_w2)
// -> f16 A-operand of the Wo GEMM.
// ---------------------------------------------------------------------------
__global__ __launch_bounds__(256) void k_gn(
    const float* __restrict__ Y, const float* __restrict__ R, const float* __restrict__ K,
    const float* __restrict__ V, const float* __restrict__ l2p,
    const float* __restrict__ gw2,
    const float* __restrict__ faaaa, const float* __restrict__ lnw,
    const float* __restrict__ lnb, _Float16* __restrict__ YG)
{
    const int t = blockIdx.y;
    const int c = blockIdx.x * 256 + threadIdx.x;
    const size_t idx = (size_t)t * C_ + c;
    __shared__ __align__(16) float gs[128];
    if (threadIdx.x < 128) {
        const size_t P = (size_t)T_ * 256;
        size_t off = (size_t)t * 256 + threadIdx.x;
        float v = ((l2p[off] + l2p[P + off]) + l2p[2 * P + off]) + l2p[3 * P + off];
        gs[threadIdx.x] = tanhf(v);
    }
    __syncthreads();
    float y = Y[idx];
    float s1 = y, s2 = y * y;
#pragma unroll
    for (int off = 1; off < 64; off <<= 1) {
        s1 += __shfl_xor(s1, off, 64);
        s2 += __shfl_xor(s2, off, 64);
    }
    float mu = s1 * (1.0f / 64.0f);
    float var = s2 * (1.0f / 64.0f) - mu * mu;
    float gn = (y - mu) * rsqrtf(var + 0.00064f) * lnw[c] + lnb[c];
    float p = R[idx] * K[idx] * faaaa[c];
#pragma unroll
    for (int off = 1; off < 64; off <<= 1) p += __shfl_xor(p, off, 64);
    float y2 = gn + p * V[idx];
    float g = 0.f;
    for (int j = 0; j < 128; ++j) g = fmaf(gs[j], gw2[(size_t)j * C_ + c], g);
    YG[idx] = (_Float16)(y2 * g);
}

// ---------------------------------------------------------------------------
extern "C" void kernel_launch(void* const* d_in, const int* in_sizes, int n_in,
                              void* d_out, int out_size, void* d_ws, size_t ws_size,
                              hipStream_t stream)
{
    (void)in_sizes; (void)n_in; (void)out_size; (void)ws_size;
    const float* hidden   = (const float*)d_in[0];
    const float* Wq       = (const float*)d_in[1];
    const float* Wk       = (const float*)d_in[2];
    const float* Wv       = (const float*)d_in[3];
    const float* Wo       = (const float*)d_in[4];
    const float* maa_x    = (const float*)d_in[5];
    const float* maa_rg   = (const float*)d_in[6];
    const float* maa_wa   = (const float*)d_in[7];
    const float* maa_k    = (const float*)d_in[8];
    const float* maa_v    = (const float*)d_in[9];
    const float* maa_w1   = (const float*)d_in[10];
    const float* maa_w2   = (const float*)d_in[11];
    const float* tdecay   = (const float*)d_in[12];
    const float* decay_w1 = (const float*)d_in[13];
    const float* decay_w2 = (const float*)d_in[14];
    const float* aaaaa    = (const float*)d_in[15];
    const float* aaa_w1   = (const float*)d_in[16];
    const float* aaa_w2   = (const float*)d_in[17];
    const float* kkk_w1   = (const float*)d_in[18];
    const float* kkk_w2   = (const float*)d_in[19];
    const float* gate_w1  = (const float*)d_in[20];
    const float* gate_w2  = (const float*)d_in[21];
    const float* misc_a   = (const float*)d_in[22];
    const float* ma_w1    = (const float*)d_in[23];
    const float* ma_w2    = (const float*)d_in[24];
    const float* misc_k   = (const float*)d_in[25];
    const float* mk_w1    = (const float*)d_in[26];
    const float* mk_w2    = (const float*)d_in[27];
    const float* faaaa    = (const float*)d_in[28];
    const float* lnw      = (const float*)d_in[29];
    const float* lnb      = (const float*)d_in[30];

    float* ws = (float*)d_ws;
    const size_t TC = (size_t)T_ * C_;
    // f32 buffers:
    //   S0: y   S2: b   S3: kk   S4: r   S5: dec   S6: k0 -> k   S7: v
    float* S0 = ws + 0 * TC;
    float* S2 = ws + 2 * TC;
    float* S3 = ws + 3 * TC;
    float* S4 = ws + 4 * TC;
    float* S5 = ws + 5 * TC;
    float* S6 = ws + 6 * TC;
    float* S7 = ws + 7 * TC;
    float* m1p = ws + 8 * TC;                    // [4][T][128] partials
    float* l2p = m1p + (size_t)4 * T_ * 128;     // [4][T][256] partials
    // f16 region
    _Float16* WTq = (_Float16*)(l2p + (size_t)4 * T_ * 256);
    _Float16* WTk = WTq + (size_t)C_ * C_;
    _Float16* WTv = WTk + (size_t)C_ * C_;
    _Float16* WTo = WTv + (size_t)C_ * C_;
    _Float16* WTm = WTo + (size_t)C_ * C_;       // [128,2048]
    _Float16* WTl = WTm + (size_t)128 * C_;      // [256,2048]
    _Float16* xxxH = WTl + (size_t)256 * C_;
    _Float16* xrgH = xxxH + TC;
    _Float16* xwaH = xrgH + TC;
    _Float16* xkH  = xwaH + TC;
    _Float16* xvH  = xkH + TC;
    _Float16* ygH  = xxxH;                       // xxxH dead after step 6
    float* out = (float*)d_out;

    // 1. transpose+convert big weights
    k_tr<<<dim3(32, 32, 4), 256, 0, stream>>>(Wq, Wk, Wv, Wo, WTq, WTk, WTv, WTo);
    // 2. pack+transpose LoRA weights (z=0: WTm, z=1: WTl)
    k_trW<<<dim3(8, 256, 2), 256, 0, stream>>>(maa_w1, gate_w1, decay_w1,
        aaa_w1, ma_w1, kkk_w1, mk_w1, WTm, WTl);
    // 3. xxxH
    k_prep<<<dim3((int)(TC / 256)), 256, 0, stream>>>(hidden, maa_x, xxxH);
    // 4. m1 partials = xxxH @ WTm^T
    k_lora<<<dim3(16, 4, 4), 256, 0, stream>>>(0, xxxH, xxxH, xxxH, xxxH,
        WTm, WTl, m1p, l2p);
    // 5. xmix -> f16 operands
    k_xmix<<<dim3(8, 64), 256, 0, stream>>>(hidden, m1p, maa_w2,
        maa_rg, maa_wa, maa_k, maa_v, xrgH, xwaH, xkH, xvH);
    // 6. l2 partials (gate | decay | aaa | ma | kkk | mk)
    k_lora<<<dim3(16, 8, 4), 256, 0, stream>>>(1, xxxH, xrgH, xwaH, xkH,
        WTm, WTl, m1p, l2p);
    // 7. r, k0, v (f16 MFMA, dbuf async staging)
    k_gemm<<<dim3(16, 8, 3), 256, 0, stream>>>(
        xrgH, WTq, S4,  xkH, WTk, S6,  xvH, WTv, S7);
    // 8. fused stage-2: dec, kk (normalized), b, k_final
    k_fuse<<<dim3(8, 64), 256, 0, stream>>>(l2p, S6, decay_w2, aaa_w2, ma_w2,
        kkk_w2, mk_w2, tdecay, aaaaa, misc_a, misc_k, S5, S3, S2);
    // 9. WKV7 scan -> y (S0)
    k_wkv<<<dim3(128), 256, 0, stream>>>(S4, S5, S6, S7, S3, S2, S0);
    // 10. groupnorm + bonus + fused gate -> f16 (reuses xxxH slot)
    k_gn<<<dim3(8, 1024), 256, 0, stream>>>(S0, S4, S6, S7, l2p, gate_w2,
        faaaa, lnw, lnb, ygH);
    // 11. out = (y*g) @ Wo
    k_gemm<<<dim3(16, 8, 1), 256, 0, stream>>>(
        ygH, WTo, out,  ygH, WTo, out,  ygH, WTo, out);
}

// Round 8
// 599.920 us; speedup vs baseline: 1.0904x; 1.0100x over previous
//
#include <hip/hip_runtime.h>

// RWKV7 attention block, MI355X/gfx950.
// B=1, T=1024, C=2048, H=32, N=64. All inputs/outputs f32.
// Big GEMMs: f16 MFMA 16x16x32, double-buffered global_load_lds(16B) staging.
// LoRA stage-1: MFMA split-K, deterministic per-split partials.
// WKV scan v5: 8 blocks/head (2 waves/CU halves per-CU LDS BW), dbuf async
// staging, software-pipelined LDS->reg reads, DPP reductions.

#define T_ 1024
#define C_ 2048
#define H_ 32
#define N_ 64

using half8  = __attribute__((ext_vector_type(8))) _Float16;  // 8 f16 (4 VGPRs)
using half4  = __attribute__((ext_vector_type(4))) _Float16;  // 8 B
using floatx4 = __attribute__((ext_vector_type(4))) float;    // 4 f32 acc

// DPP xor-add within 16-lane rows: quad_perm(0xB1)=xor1, quad_perm(0x4E)=xor2,
// row_half_mirror(0x141)=xor4, row_mirror(0x140)=xor8.
#define DPP_ADD(v, ctrl) \
    ((v) + __int_as_float(__builtin_amdgcn_update_dpp( \
        0, __float_as_int(v), (ctrl), 0xf, 0xf, true)))
#define REDUCE16(v) do { \
    v = DPP_ADD(v, 0xB1); v = DPP_ADD(v, 0x4E); \
    v = DPP_ADD(v, 0x141); v = DPP_ADD(v, 0x140); } while (0)

// async 16B global->LDS (direct-to-LDS DMA; HW dest = wave base + lane*16,
// all call sites construct per-lane lds ptrs matching exactly that layout)
__device__ __forceinline__ void async_cp16(const void* g, void* l) {
    __builtin_amdgcn_global_load_lds(
        (const __attribute__((address_space(1))) void*)g,
        (__attribute__((address_space(3))) void*)l, 16, 0, 0);
}

// ---------------------------------------------------------------------------
// Transpose + convert big weights: W[k][n] f32 -> WT[n][k] f16
// ---------------------------------------------------------------------------
__global__ __launch_bounds__(256) void k_tr(
    const float* __restrict__ W0, const float* __restrict__ W1,
    const float* __restrict__ W2, const float* __restrict__ W3,
    _Float16* __restrict__ D0, _Float16* __restrict__ D1,
    _Float16* __restrict__ D2, _Float16* __restrict__ D3)
{
    const int z = blockIdx.z;
    const float* S = (z == 0) ? W0 : (z == 1) ? W1 : (z == 2) ? W2 : W3;
    _Float16* D = (z == 0) ? D0 : (z == 1) ? D1 : (z == 2) ? D2 : D3;
    const int nb = blockIdx.x * 64, kb = blockIdx.y * 64;
    __shared__ __align__(16) float tile[64][65];
    const int tr = threadIdx.x >> 4, tc4 = (threadIdx.x & 15) * 4;
#pragma unroll
    for (int p = 0; p < 4; ++p) {
        int row = p * 16 + tr;
        float4 v = *(const float4*)&S[(size_t)(kb + row) * C_ + nb + tc4];
        tile[row][tc4 + 0] = v.x; tile[row][tc4 + 1] = v.y;
        tile[row][tc4 + 2] = v.z; tile[row][tc4 + 3] = v.w;
    }
    __syncthreads();
#pragma unroll
    for (int p = 0; p < 4; ++p) {
        int n = p * 16 + tr;
        half4 u;
        u[0] = (_Float16)tile[tc4 + 0][n];
        u[1] = (_Float16)tile[tc4 + 1][n];
        u[2] = (_Float16)tile[tc4 + 2][n];
        u[3] = (_Float16)tile[tc4 + 3][n];
        *(half4*)&D[(size_t)(nb + n) * C_ + kb + tc4] = u;
    }
}

// ---------------------------------------------------------------------------
// Pack+transpose LoRA weights to f16 WT[n][k].
// z=0: WT_m [128][2048] <- maa_w1[2048,128]
// z=1: WT_l [256][2048] <- gate(128) | decay(64) | aaa(16) | ma(16) | kkk(16) | mk(16)
// ---------------------------------------------------------------------------
__global__ __launch_bounds__(256) void k_trW(
    const float* __restrict__ maa_w1, const float* __restrict__ gate_w1,
    const float* __restrict__ decay_w1, const float* __restrict__ aaa_w1,
    const float* __restrict__ ma_w1, const float* __restrict__ kkk_w1,
    const float* __restrict__ mk_w1,
    _Float16* __restrict__ WTm, _Float16* __restrict__ WTl)
{
    const int z = blockIdx.z;
    const int k = blockIdx.x * 256 + threadIdx.x;   // 0..2047
    const int n = blockIdx.y;
    if (z == 0 && n >= 128) return;
    const float* src; int stride, col;
    _Float16* dst;
    if (z == 0) { src = maa_w1; stride = 128; col = n; dst = WTm; }
    else {
        dst = WTl;
        if (n < 128)      { src = gate_w1;  stride = 128; col = n; }
        else if (n < 192) { src = decay_w1; stride = 64;  col = n - 128; }
        else if (n < 208) { src = aaa_w1;   stride = 16;  col = n - 192; }
        else if (n < 224) { src = ma_w1;    stride = 16;  col = n - 208; }
        else if (n < 240) { src = kkk_w1;   stride = 16;  col = n - 224; }
        else              { src = mk_w1;    stride = 16;  col = n - 240; }
    }
    dst[(size_t)n * C_ + k] = (_Float16)src[(size_t)k * stride + col];
}

// ---------------------------------------------------------------------------
// xxxH = f16( x + (x_prev - x) * maa_x )
// ---------------------------------------------------------------------------
__global__ __launch_bounds__(256) void k_prep(
    const float* __restrict__ X, const float* __restrict__ maa_x,
    _Float16* __restrict__ xxxH)
{
    const size_t idx = (size_t)blockIdx.x * 256 + threadIdx.x;
    const int c = (int)(idx & (C_ - 1));
    float cur = X[idx];
    float prev = (idx >= C_) ? X[idx - C_] : 0.0f;
    xxxH[idx] = (_Float16)(cur + (prev - cur) * maa_x[c]);
}

// ---------------------------------------------------------------------------
// LoRA MFMA GEMM, split-K -> per-split partials (deterministic; no atomics).
// BM=64, BN=32, BK=32, ksplit=4.
// which=0: m1p[ks][1024][128] = xxxH @ WTm^T (4 n-tiles)
// which=1: l2p[ks][1024][256], A per n-tile: 0-3 xrg | 4-6 xwa | 7 xk
// ---------------------------------------------------------------------------
__global__ __launch_bounds__(256) void k_lora(
    int which,
    const _Float16* __restrict__ Axxx, const _Float16* __restrict__ Axrg,
    const _Float16* __restrict__ Axwa, const _Float16* __restrict__ Axk,
    const _Float16* __restrict__ WTm, const _Float16* __restrict__ WTl,
    float* __restrict__ m1p, float* __restrict__ l2p)
{
    const int mt = blockIdx.x;      // 16 tiles of 64 rows
    const int nt = blockIdx.y;      // tiles of 32 cols
    const int ks = blockIdx.z;      // 4 K-chunks of 512
    const _Float16* A; const _Float16* BT; float* O; int ostride;
    if (which == 0) { A = Axxx; BT = WTm; O = m1p; ostride = 128; }
    else {
        BT = WTl; O = l2p; ostride = 256;
        A = (nt < 4) ? Axrg : (nt < 7) ? Axwa : Axk;
    }
    O += (size_t)ks * T_ * ostride;
    const int m0 = mt * 64, n0 = nt * 32, k0 = ks * 512;
    const int tid = threadIdx.x;
    __shared__ __align__(16) _Float16 As[64 * 40];
    __shared__ __align__(16) _Float16 Bs[32 * 40];
    const int lane = tid & 63, wv = tid >> 6;
    const int r16 = lane & 15, q = lane >> 4;

    floatx4 acc[2];
    { floatx4 zv = {0.f, 0.f, 0.f, 0.f}; acc[0] = zv; acc[1] = zv; }

    const int arow = tid >> 2, ac8 = (tid & 3) * 8;
    const _Float16* ag = A + (size_t)(m0 + arow) * C_ + k0 + ac8;
    const _Float16* bg = BT + (size_t)(n0 + (tid >> 2)) * C_ + k0 + ac8;

    for (int kc = 0; kc < 512; kc += 32) {
        half8 av = *(const half8*)(ag + kc);
        half8 bv;
        if (tid < 128) bv = *(const half8*)(bg + kc);
        *(half8*)&As[arow * 40 + ac8] = av;
        if (tid < 128) *(half8*)&Bs[(tid >> 2) * 40 + ac8] = bv;
        __syncthreads();
        half8 af = *(const half8*)&As[(wv * 16 + r16) * 40 + q * 8];
        half8 b0 = *(const half8*)&Bs[(r16) * 40 + q * 8];
        half8 b1 = *(const half8*)&Bs[(16 + r16) * 40 + q * 8];
        acc[0] = __builtin_amdgcn_mfma_f32_16x16x32_f16(af, b0, acc[0], 0, 0, 0);
        acc[1] = __builtin_amdgcn_mfma_f32_16x16x32_f16(af, b1, acc[1], 0, 0, 0);
        __syncthreads();
    }
#pragma unroll
    for (int j = 0; j < 2; ++j)
#pragma unroll
        for (int e = 0; e < 4; ++e) {
            int row = m0 + wv * 16 + q * 4 + e;
            int col = n0 + j * 16 + r16;
            O[(size_t)row * ostride + col] = acc[j][e];
        }
}

// ---------------------------------------------------------------------------
// xmix: m1 = sum_ks(m1p), tanh; mix = einsum(m1[T,4,32], maa_w2[4,32,C]);
// emit f16 GEMM operands xrgH/xwaH/xkH/xvH.
// ---------------------------------------------------------------------------
__global__ __launch_bounds__(256) void k_xmix(
    const float* __restrict__ X, const float* __restrict__ m1p,
    const float* __restrict__ w2,
    const float* __restrict__ mrg, const float* __restrict__ mwa,
    const float* __restrict__ mk, const float* __restrict__ mv,
    _Float16* __restrict__ xrgH, _Float16* __restrict__ xwaH,
    _Float16* __restrict__ xkH, _Float16* __restrict__ xvH)
{
    const int tid = threadIdx.x;
    const int c = blockIdx.x * 256 + tid;
    const int t0 = blockIdx.y * 16;
    const size_t P = (size_t)T_ * 128;
    __shared__ __align__(16) float m1s[16][128];
#pragma unroll
    for (int p = 0; p < 2; ++p) {
        int id = tid + p * 256;
        int r = id >> 5, c4 = (id & 31) * 4;
        size_t off = (size_t)(t0 + r) * 128 + c4;
        float4 v0 = *(const float4*)&m1p[off];
        float4 v1 = *(const float4*)&m1p[P + off];
        float4 v2 = *(const float4*)&m1p[2 * P + off];
        float4 v3 = *(const float4*)&m1p[3 * P + off];
        float4 v;
        v.x = tanhf(((v0.x + v1.x) + v2.x) + v3.x);
        v.y = tanhf(((v0.y + v1.y) + v2.y) + v3.y);
        v.z = tanhf(((v0.z + v1.z) + v2.z) + v3.z);
        v.w = tanhf(((v0.w + v1.w) + v2.w) + v3.w);
        *(float4*)&m1s[r][c4] = v;
    }
    __syncthreads();
    float a0[16], a1[16], a2[16], a3[16];
#pragma unroll
    for (int t = 0; t < 16; ++t) { a0[t] = 0.f; a1[t] = 0.f; a2[t] = 0.f; a3[t] = 0.f; }
    for (int d = 0; d < 32; ++d) {
        float w0 = w2[(size_t)(0 * 32 + d) * C_ + c];
        float w1 = w2[(size_t)(1 * 32 + d) * C_ + c];
        float w2v = w2[(size_t)(2 * 32 + d) * C_ + c];
        float w3 = w2[(size_t)(3 * 32 + d) * C_ + c];
#pragma unroll
        for (int t = 0; t < 16; ++t) {
            a0[t] = fmaf(m1s[t][d],      w0,  a0[t]);
            a1[t] = fmaf(m1s[t][32 + d], w1,  a1[t]);
            a2[t] = fmaf(m1s[t][64 + d], w2v, a2[t]);
            a3[t] = fmaf(m1s[t][96 + d], w3,  a3[t]);
        }
    }
    float vrg = mrg[c], vwa = mwa[c], vmk = mk[c], vmv = mv[c];
    float prev = (t0 > 0) ? X[(size_t)(t0 - 1) * C_ + c] : 0.0f;
    for (int t = 0; t < 16; ++t) {
        size_t idx = (size_t)(t0 + t) * C_ + c;
        float cur = X[idx];
        float dx = prev - cur;
        xrgH[idx] = (_Float16)(cur + dx * (vrg + a0[t]));
        xwaH[idx] = (_Float16)(cur + dx * (vwa + a1[t]));
        xkH[idx]  = (_Float16)(cur + dx * (vmk + a2[t]));
        xvH[idx]  = (_Float16)(cur + dx * (vmv + a3[t]));
        prev = cur;
    }
}

// ---------------------------------------------------------------------------
// f16 MFMA GEMM: C[1024,2048] = A(f16) @ W via WT[n][k] f16.
// BM=BN=128, BK=32, 256 thr (4 waves 2x2), 4x4 16x16x32 tiles/wave.
// Double-buffered global_load_lds staging.
// ---------------------------------------------------------------------------
__global__ __launch_bounds__(256) void k_gemm(
    const _Float16* __restrict__ A0, const _Float16* __restrict__ B0, float* __restrict__ C0,
    const _Float16* __restrict__ A1, const _Float16* __restrict__ B1, float* __restrict__ C1,
    const _Float16* __restrict__ A2, const _Float16* __restrict__ B2, float* __restrict__ C2)
{
    const int z = blockIdx.z;
    const _Float16* A = (z == 0) ? A0 : (z == 1) ? A1 : A2;
    const _Float16* Bt = (z == 0) ? B0 : (z == 1) ? B1 : B2;
    float* C = (z == 0) ? C0 : (z == 1) ? C1 : C2;
    const int mtile = blockIdx.y * 128;
    const int ntile = blockIdx.x * 128;
    const int tid = threadIdx.x;
    __shared__ __align__(16) _Float16 As[2][128 * 32];  // unpadded (async layout)
    __shared__ __align__(16) _Float16 Bs[2][128 * 32];
    const int lane = tid & 63;
    const int wvid = tid >> 6;
    const int wm = wvid >> 1, wn = wvid & 1;
    const int r16 = lane & 15, q = lane >> 4;

    floatx4 acc[4][4];
#pragma unroll
    for (int i = 0; i < 4; ++i)
#pragma unroll
        for (int j = 0; j < 4; ++j) { floatx4 zv = {0.f, 0.f, 0.f, 0.f}; acc[i][j] = zv; }

    const int srow = tid >> 2, sq = tid & 3;
    const _Float16* agA = A + (size_t)(mtile + srow) * C_ + sq * 8;
    const _Float16* agB = Bt + (size_t)(ntile + srow) * C_ + sq * 8;
    const int ldso = srow * 32 + sq * 8;
    const size_t rowoff = (size_t)64 * C_;

    async_cp16(agA, &As[0][ldso]);
    async_cp16(agA + rowoff, &As[0][ldso + 64 * 32]);
    async_cp16(agB, &Bs[0][ldso]);
    async_cp16(agB + rowoff, &Bs[0][ldso + 64 * 32]);

    for (int kc = 0; kc < C_; kc += 32) {
        const int p = (kc >> 5) & 1;
        __syncthreads();                      // buf p ready (drains copies)
        if (kc + 32 < C_) {                   // prefetch k+1 into buf p^1
            async_cp16(agA + kc + 32, &As[p ^ 1][ldso]);
            async_cp16(agA + kc + 32 + rowoff, &As[p ^ 1][ldso + 64 * 32]);
            async_cp16(agB + kc + 32, &Bs[p ^ 1][ldso]);
            async_cp16(agB + kc + 32 + rowoff, &Bs[p ^ 1][ldso + 64 * 32]);
        }
        half8 af[4], bf[4];
#pragma unroll
        for (int i = 0; i < 4; ++i)
            af[i] = *(const half8*)&As[p][(wm * 64 + i * 16 + r16) * 32 + q * 8];
#pragma unroll
        for (int j = 0; j < 4; ++j)
            bf[j] = *(const half8*)&Bs[p][(wn * 64 + j * 16 + r16) * 32 + q * 8];
#pragma unroll
        for (int i = 0; i < 4; ++i)
#pragma unroll
            for (int j = 0; j < 4; ++j)
                acc[i][j] = __builtin_amdgcn_mfma_f32_16x16x32_f16(af[i], bf[j], acc[i][j], 0, 0, 0);
    }
    // C/D layout: col = lane&15, row = (lane>>4)*4 + reg
#pragma unroll
    for (int i = 0; i < 4; ++i)
#pragma unroll
        for (int j = 0; j < 4; ++j)
#pragma unroll
            for (int e = 0; e < 4; ++e) {
                int row = mtile + wm * 64 + i * 16 + q * 4 + e;
                int col = ntile + wn * 64 + j * 16 + r16;
                C[(size_t)row * C_ + col] = acc[i][j][e];
            }
}

// ---------------------------------------------------------------------------
// Fused stage-2: dec=exp(w), kk (normalized), b = kk*a, k_final.
// l2p partials [4][T][256]: cols 128-191 decay(tanh) | 192-207 aaa |
// 208-223 ma | 224-239 kkk(tanh) | 240-255 mk. Fixed-order reduce.
// ---------------------------------------------------------------------------
__global__ __launch_bounds__(256) void k_fuse(
    const float* __restrict__ l2p,
    float* __restrict__ K0,
    const float* __restrict__ decay_w2, const float* __restrict__ aaa_w2,
    const float* __restrict__ ma_w2, const float* __restrict__ kkk_w2,
    const float* __restrict__ mk_w2,
    const float* __restrict__ tdecay, const float* __restrict__ aaaaa,
    const float* __restrict__ misc_a, const float* __restrict__ misc_k,
    float* __restrict__ Dout, float* __restrict__ KKout, float* __restrict__ Bout)
{
    const int tid = threadIdx.x;
    const int c = blockIdx.x * 256 + tid;
    const int t0 = blockIdx.y * 16;
    const size_t P = (size_t)T_ * 256;
    __shared__ __align__(16) float wsS[16][96];   // decay64 | aaa16 | ma16
    __shared__ __align__(16) float ksS[16][32];   // kkk16 | mk16
    for (int id = tid; id < 16 * 24; id += 256) {
        int r = id / 24, c4 = (id % 24) * 4;
        size_t off = (size_t)(t0 + r) * 256 + 128 + c4;
        float4 v0 = *(const float4*)&l2p[off];
        float4 v1 = *(const float4*)&l2p[P + off];
        float4 v2 = *(const float4*)&l2p[2 * P + off];
        float4 v3 = *(const float4*)&l2p[3 * P + off];
        float4 v;
        v.x = ((v0.x + v1.x) + v2.x) + v3.x;
        v.y = ((v0.y + v1.y) + v2.y) + v3.y;
        v.z = ((v0.z + v1.z) + v2.z) + v3.z;
        v.w = ((v0.w + v1.w) + v2.w) + v3.w;
        if (c4 < 64) { v.x = tanhf(v.x); v.y = tanhf(v.y); v.z = tanhf(v.z); v.w = tanhf(v.w); }
        *(float4*)&wsS[r][c4] = v;
    }
    for (int id = tid; id < 16 * 8; id += 256) {
        int r = id / 8, c4 = (id % 8) * 4;
        size_t off = (size_t)(t0 + r) * 256 + 224 + c4;
        float4 v0 = *(const float4*)&l2p[off];
        float4 v1 = *(const float4*)&l2p[P + off];
        float4 v2 = *(const float4*)&l2p[2 * P + off];
        float4 v3 = *(const float4*)&l2p[3 * P + off];
        float4 v;
        v.x = ((v0.x + v1.x) + v2.x) + v3.x;
        v.y = ((v0.y + v1.y) + v2.y) + v3.y;
        v.z = ((v0.z + v1.z) + v2.z) + v3.z;
        v.w = ((v0.w + v1.w) + v2.w) + v3.w;
        if (c4 < 16) { v.x = tanhf(v.x); v.y = tanhf(v.y); v.z = tanhf(v.z); v.w = tanhf(v.w); }
        *(float4*)&ksS[r][c4] = v;
    }
    __syncthreads();
    float accW[16], accA[16], accMA[16], accKK[16], accMK[16];
#pragma unroll
    for (int r = 0; r < 16; ++r) { accW[r] = 0.f; accA[r] = 0.f; accMA[r] = 0.f; accKK[r] = 0.f; accMK[r] = 0.f; }
    for (int j = 0; j < 64; ++j) {
        float w = decay_w2[(size_t)j * C_ + c];
#pragma unroll
        for (int r = 0; r < 16; ++r) accW[r] = fmaf(wsS[r][j], w, accW[r]);
    }
    for (int j = 0; j < 16; ++j) {
        float wa = aaa_w2[(size_t)j * C_ + c];
        float wm = ma_w2[(size_t)j * C_ + c];
        float wk = kkk_w2[(size_t)j * C_ + c];
        float wq = mk_w2[(size_t)j * C_ + c];
#pragma unroll
        for (int r = 0; r < 16; ++r) {
            accA[r]  = fmaf(wsS[r][64 + j], wa, accA[r]);
            accMA[r] = fmaf(wsS[r][80 + j], wm, accMA[r]);
            accKK[r] = fmaf(ksS[r][j],      wk, accKK[r]);
            accMK[r] = fmaf(ksS[r][16 + j], wq, accMK[r]);
        }
    }
    float td = tdecay[c], aa = aaaaa[c], mia = misc_a[c], mik = misc_k[c];
    for (int r = 0; r < 16; ++r) {
        size_t idx = (size_t)(t0 + r) * C_ + c;
        float wraw = td + accW[r];
        float w = -logf(1.0f + __expf(-wraw)) - 0.5f;   // -softplus(-x) - 0.5
        float a  = 1.0f / (1.0f + __expf(-(aa  + accA[r])));
        float mav = 1.0f / (1.0f + __expf(-(mia + accMA[r])));
        float mkv = 1.0f / (1.0f + __expf(-(mik + accMK[r])));
        float k0 = K0[idx];
        float kkun = k0 + accKK[r];
        float ss = kkun * kkun;
        REDUCE16(ss);
        ss += __shfl_xor(ss, 16, 64);
        ss += __shfl_xor(ss, 32, 64);
        float kn = kkun * (1.0f / fmaxf(sqrtf(ss), 1e-12f));
        Dout[idx]  = __expf(w);                 // dec, precomputed for the scan
        KKout[idx] = kn;
        Bout[idx]  = kn * a;
        K0[idx]    = k0 * (mav + a * (1.0f - mav)) * __expf(fminf(w * mkv, 0.0f));
    }
}

// ---------------------------------------------------------------------------
// WKV7 scan v5: 8 blocks/head (8 rows each) -> 256 blocks, 128 thr (2 waves).
// Dbuf async LDS staging + software-pipelined LDS->reg reads (step tt+1
// loaded while computing tt). Wave = 4 row-slots x 16 j-groups.
// ---------------------------------------------------------------------------
__global__ __launch_bounds__(128) void k_wkv(
    const float* __restrict__ R, const float* __restrict__ DEC,
    const float* __restrict__ K, const float* __restrict__ V,
    const float* __restrict__ KK, const float* __restrict__ Bb,
    float* __restrict__ Y)
{
    const int tid = threadIdx.x;
    const int h = blockIdx.x >> 3;
    const int rg = blockIdx.x & 7;
    const int c0 = h * 64;
    const int wv = tid >> 6, lane = tid & 63;
    const int rowslot = lane >> 4;                     // 0..3
    const int lrow = wv * 4 + rowslot;                 // block-local row 0..7
    const int irow = rg * 8 + lrow;                    // row within head
    const int jg = lane & 15, j4 = jg * 4;

    // [buf][step][64] j-arrays + [buf][step][8] v — all async-copy layouts:
    // slot s (=staging thread or thread+128) maps to byte offset s*16.
    __shared__ __align__(16) float rS[2][16][64], dS[2][16][64], kS[2][16][64],
                                   aS[2][16][64], bS[2][16][64];
    __shared__ __align__(16) float vS[2][16][8];

    // j-array staging: slots tid and tid+128 -> (step = s>>4, quad = s&15)
    const int s0_step = tid >> 4, s0_q4 = (tid & 15) * 4;
    const int s1_step = (tid + 128) >> 4, s1_q4 = ((tid + 128) & 15) * 4;
    // v staging (threads 0..31): step = tid>>1, quad = tid&1
    const int v_step = tid >> 1, v_q4 = (tid & 1) * 4;

#define WKV_STAGE(buf, tcb) do {                                              \
    size_t g0 = (size_t)((tcb) + s0_step) * C_ + c0 + s0_q4;                  \
    size_t g1 = (size_t)((tcb) + s1_step) * C_ + c0 + s1_q4;                  \
    async_cp16(&R[g0],   &rS[buf][s0_step][s0_q4]);                           \
    async_cp16(&R[g1],   &rS[buf][s1_step][s1_q4]);                           \
    async_cp16(&DEC[g0], &dS[buf][s0_step][s0_q4]);                           \
    async_cp16(&DEC[g1], &dS[buf][s1_step][s1_q4]);                           \
    async_cp16(&K[g0],   &kS[buf][s0_step][s0_q4]);                           \
    async_cp16(&K[g1],   &kS[buf][s1_step][s1_q4]);                           \
    async_cp16(&KK[g0],  &aS[buf][s0_step][s0_q4]);                           \
    async_cp16(&KK[g1],  &aS[buf][s1_step][s1_q4]);                           \
    async_cp16(&Bb[g0],  &bS[buf][s0_step][s0_q4]);                           \
    async_cp16(&Bb[g1],  &bS[buf][s1_step][s1_q4]);                           \
    if (tid < 32)                                                             \
        async_cp16(&V[(size_t)((tcb) + v_step) * C_ + c0 + rg * 8 + v_q4],    \
                   &vS[buf][v_step][v_q4]);                                   \
} while (0)

    WKV_STAGE(0, 0);

    float4 s = make_float4(0.f, 0.f, 0.f, 0.f);

    for (int tc = 0; tc < T_; tc += 16) {
        const int p = (tc >> 4) & 1;
        __syncthreads();                               // buf p ready
        if (tc + 16 < T_) WKV_STAGE(p ^ 1, tc + 16);   // prefetch next chunk

        // software pipeline: load step tt+1 while computing tt
        float4 cr = *(float4*)&rS[p][0][j4];
        float4 cd = *(float4*)&dS[p][0][j4];
        float4 ck = *(float4*)&kS[p][0][j4];
        float4 ca = *(float4*)&aS[p][0][j4];
        float4 cb = *(float4*)&bS[p][0][j4];
        float   cv = vS[p][0][lrow];
#pragma unroll
        for (int tt = 0; tt < 16; ++tt) {
            float4 nr, nd, nk, na, nb; float nv = 0.f;
            if (tt < 15) {
                nr = *(float4*)&rS[p][tt + 1][j4];
                nd = *(float4*)&dS[p][tt + 1][j4];
                nk = *(float4*)&kS[p][tt + 1][j4];
                na = *(float4*)&aS[p][tt + 1][j4];
                nb = *(float4*)&bS[p][tt + 1][j4];
                nv = vS[p][tt + 1][lrow];
            }
            float sa = -(s.x * ca.x + s.y * ca.y + s.z * ca.z + s.w * ca.w);
            REDUCE16(sa);
            s.x = fmaf(s.x, cd.x, fmaf(sa, cb.x, cv * ck.x));
            s.y = fmaf(s.y, cd.y, fmaf(sa, cb.y, cv * ck.y));
            s.z = fmaf(s.z, cd.z, fmaf(sa, cb.z, cv * ck.z));
            s.w = fmaf(s.w, cd.w, fmaf(sa, cb.w, cv * ck.w));
            float o = s.x * cr.x + s.y * cr.y + s.z * cr.z + s.w * cr.w;
            REDUCE16(o);
            if (jg == 0) Y[(size_t)(tc + tt) * C_ + c0 + irow] = o;
            cr = nr; cd = nd; ck = nk; ca = na; cb = nb; cv = nv;
        }
    }
#undef WKV_STAGE
}

// ---------------------------------------------------------------------------
// GroupNorm + bonus + fused gate, t-tiled (16 t/block so the 128 gw2 loads
// amortize): YG = f16((gn(y) + bonus) * (tanh(l2 sum) @ gate_w2)).
// ---------------------------------------------------------------------------
__global__ __launch_bounds__(256) void k_gn(
    const float* __restrict__ Y, const float* __restrict__ R, const float* __restrict__ K,
    const float* __restrict__ V, const float* __restrict__ l2p,
    const float* __restrict__ gw2,
    const float* __restrict__ faaaa, const float* __restrict__ lnw,
    const float* __restrict__ lnb, _Float16* __restrict__ YG)
{
    const int tid = threadIdx.x;
    const int c = blockIdx.x * 256 + tid;
    const int t0 = blockIdx.y * 16;
    const size_t P = (size_t)T_ * 256;
    __shared__ __align__(16) float gs[16][128];
    for (int id = tid; id < 16 * 128; id += 256) {
        int r = id >> 7, cc = id & 127;
        size_t off = (size_t)(t0 + r) * 256 + cc;
        float v = ((l2p[off] + l2p[P + off]) + l2p[2 * P + off]) + l2p[3 * P + off];
        gs[r][cc] = tanhf(v);
    }
    __syncthreads();
    float gacc[16];
#pragma unroll
    for (int r = 0; r < 16; ++r) gacc[r] = 0.f;
    for (int j = 0; j < 128; ++j) {
        float w = gw2[(size_t)j * C_ + c];
#pragma unroll
        for (int r = 0; r < 16; ++r) gacc[r] = fmaf(gs[r][j], w, gacc[r]);
    }
    float fa = faaaa[c], lw = lnw[c], lb = lnb[c];
    for (int r = 0; r < 16; ++r) {
        const size_t idx = (size_t)(t0 + r) * C_ + c;
        float y = Y[idx];
        float s1 = y, s2 = y * y;
#pragma unroll
        for (int off = 1; off < 64; off <<= 1) {
            s1 += __shfl_xor(s1, off, 64);
            s2 += __shfl_xor(s2, off, 64);
        }
        float mu = s1 * (1.0f / 64.0f);
        float var = s2 * (1.0f / 64.0f) - mu * mu;
        float gn = (y - mu) * rsqrtf(var + 0.00064f) * lw + lb;
        float p = R[idx] * K[idx] * fa;
#pragma unroll
        for (int off = 1; off < 64; off <<= 1) p += __shfl_xor(p, off, 64);
        float y2 = gn + p * V[idx];
        YG[idx] = (_Float16)(y2 * gacc[r]);
    }
}

// ---------------------------------------------------------------------------
extern "C" void kernel_launch(void* const* d_in, const int* in_sizes, int n_in,
                              void* d_out, int out_size, void* d_ws, size_t ws_size,
                              hipStream_t stream)
{
    (void)in_sizes; (void)n_in; (void)out_size; (void)ws_size;
    const float* hidden   = (const float*)d_in[0];
    const float* Wq       = (const float*)d_in[1];
    const float* Wk       = (const float*)d_in[2];
    const float* Wv       = (const float*)d_in[3];
    const float* Wo       = (const float*)d_in[4];
    const float* maa_x    = (const float*)d_in[5];
    const float* maa_rg   = (const float*)d_in[6];
    const float* maa_wa   = (const float*)d_in[7];
    const float* maa_k    = (const float*)d_in[8];
    const float* maa_v    = (const float*)d_in[9];
    const float* maa_w1   = (const float*)d_in[10];
    const float* maa_w2   = (const float*)d_in[11];
    const float* tdecay   = (const float*)d_in[12];
    const float* decay_w1 = (const float*)d_in[13];
    const float* decay_w2 = (const float*)d_in[14];
    const float* aaaaa    = (const float*)d_in[15];
    const float* aaa_w1   = (const float*)d_in[16];
    const float* aaa_w2   = (const float*)d_in[17];
    const float* kkk_w1   = (const float*)d_in[18];
    const float* kkk_w2   = (const float*)d_in[19];
    const float* gate_w1  = (const float*)d_in[20];
    const float* gate_w2  = (const float*)d_in[21];
    const float* misc_a   = (const float*)d_in[22];
    const float* ma_w1    = (const float*)d_in[23];
    const float* ma_w2    = (const float*)d_in[24];
    const float* misc_k   = (const float*)d_in[25];
    const float* mk_w1    = (const float*)d_in[26];
    const float* mk_w2    = (const float*)d_in[27];
    const float* faaaa    = (const float*)d_in[28];
    const float* lnw      = (const float*)d_in[29];
    const float* lnb      = (const float*)d_in[30];

    float* ws = (float*)d_ws;
    const size_t TC = (size_t)T_ * C_;
    // f32 buffers:
    //   S0: y   S2: b   S3: kk   S4: r   S5: dec   S6: k0 -> k   S7: v
    float* S0 = ws + 0 * TC;
    float* S2 = ws + 2 * TC;
    float* S3 = ws + 3 * TC;
    float* S4 = ws + 4 * TC;
    float* S5 = ws + 5 * TC;
    float* S6 = ws + 6 * TC;
    float* S7 = ws + 7 * TC;
    float* m1p = ws + 8 * TC;                    // [4][T][128] partials
    float* l2p = m1p + (size_t)4 * T_ * 128;     // [4][T][256] partials
    // f16 region
    _Float16* WTq = (_Float16*)(l2p + (size_t)4 * T_ * 256);
    _Float16* WTk = WTq + (size_t)C_ * C_;
    _Float16* WTv = WTk + (size_t)C_ * C_;
    _Float16* WTo = WTv + (size_t)C_ * C_;
    _Float16* WTm = WTo + (size_t)C_ * C_;       // [128,2048]
    _Float16* WTl = WTm + (size_t)128 * C_;      // [256,2048]
    _Float16* xxxH = WTl + (size_t)256 * C_;
    _Float16* xrgH = xxxH + TC;
    _Float16* xwaH = xrgH + TC;
    _Float16* xkH  = xwaH + TC;
    _Float16* xvH  = xkH + TC;
    _Float16* ygH  = xxxH;                       // xxxH dead after step 6
    float* out = (float*)d_out;

    // 1. transpose+convert big weights
    k_tr<<<dim3(32, 32, 4), 256, 0, stream>>>(Wq, Wk, Wv, Wo, WTq, WTk, WTv, WTo);
    // 2. pack+transpose LoRA weights (z=0: WTm, z=1: WTl)
    k_trW<<<dim3(8, 256, 2), 256, 0, stream>>>(maa_w1, gate_w1, decay_w1,
        aaa_w1, ma_w1, kkk_w1, mk_w1, WTm, WTl);
    // 3. xxxH
    k_prep<<<dim3((int)(TC / 256)), 256, 0, stream>>>(hidden, maa_x, xxxH);
    // 4. m1 partials = xxxH @ WTm^T
    k_lora<<<dim3(16, 4, 4), 256, 0, stream>>>(0, xxxH, xxxH, xxxH, xxxH,
        WTm, WTl, m1p, l2p);
    // 5. xmix -> f16 operands
    k_xmix<<<dim3(8, 64), 256, 0, stream>>>(hidden, m1p, maa_w2,
        maa_rg, maa_wa, maa_k, maa_v, xrgH, xwaH, xkH, xvH);
    // 6. l2 partials (gate | decay | aaa | ma | kkk | mk)
    k_lora<<<dim3(16, 8, 4), 256, 0, stream>>>(1, xxxH, xrgH, xwaH, xkH,
        WTm, WTl, m1p, l2p);
    // 7. r, k0, v (f16 MFMA, dbuf async staging)
    k_gemm<<<dim3(16, 8, 3), 256, 0, stream>>>(
        xrgH, WTq, S4,  xkH, WTk, S6,  xvH, WTv, S7);
    // 8. fused stage-2: dec, kk (normalized), b, k_final
    k_fuse<<<dim3(8, 64), 256, 0, stream>>>(l2p, S6, decay_w2, aaa_w2, ma_w2,
        kkk_w2, mk_w2, tdecay, aaaaa, misc_a, misc_k, S5, S3, S2);
    // 9. WKV7 scan -> y (S0)
    k_wkv<<<dim3(256), 128, 0, stream>>>(S4, S5, S6, S7, S3, S2, S0);
    // 10. groupnorm + bonus + fused gate -> f16 (reuses xxxH slot)
    k_gn<<<dim3(8, 64), 256, 0, stream>>>(S0, S4, S6, S7, l2p, gate_w2,
        faaaa, lnw, lnb, ygH);
    // 11. out = (y*g) @ Wo
    k_gemm<<<dim3(16, 8, 1), 256, 0, stream>>>(
        ygH, WTo, out,  ygH, WTo, out,  ygH, WTo, out);
}